// Round 1
// baseline (800.903 us; speedup 1.0000x reference)
//
#include <hip/hip_runtime.h>

#define N_NODES 20000
#define N_EDGES 320000
#define INV_SQRT3 0.5773502691896258f

typedef unsigned short u16;
typedef unsigned int u32;
typedef __attribute__((ext_vector_type(8))) short short8;
typedef __attribute__((ext_vector_type(4))) float f32x4;

// ---- workspace layout (bytes) ----
static const size_t OFF_NSBF = 0;         // N*64 bf16   = 2,560,000
static const size_t OFF_SUP  = 2560000;   // N*64 f32    = 5,120,000
static const size_t OFF_VUP  = 7680000;   // N*192 f32   = 15,360,000
static const size_t OFF_W1F  = 23040000;  // 5*4*64*8 bf16 = 20480
static const size_t OFF_W2F  = 23060480;  // 2*4*64*8 bf16 = 8192
static const size_t OFF_W3F  = 23068672;  // 2*16*64*8 bf16 = 32768
static const size_t OFF_CNT  = 23101440;  // N int = 80000
static const size_t OFF_OFFS = 23181440;  // (N+1) int = 80004
static const size_t OFF_CUR  = 23261444;  // N int = 80000
static const size_t OFF_SORT = 23341444;  // E int = 1,280,000

static __device__ __forceinline__ u16 f2bf(float x) {
    union { float f; u32 u; } c; c.f = x;
    u32 u = c.u + 0x7fffu + ((c.u >> 16) & 1u);
    return (u16)(u >> 16);
}
static __device__ __forceinline__ f32x4 mfma16(short8 a, short8 b, f32x4 c) {
    return __builtin_amdgcn_mfma_f32_16x16x32_bf16(a, b, c, 0, 0, 0);
}
static __device__ __forceinline__ float silu(float x) {
    return x / (1.0f + __expf(-x));
}

// ---- prep: weights -> MFMA B-fragment order (bf16) ----
__global__ void prep_w_kernel(const float* __restrict__ W1, const float* __restrict__ W2,
                              const float* __restrict__ W3,
                              u16* __restrict__ W1f, u16* __restrict__ W2f, u16* __restrict__ W3f) {
    int t = blockIdx.x * 256 + threadIdx.x;
    if (t >= 3840) return;
    int l = t & 63, grp = t >> 6;
    int hi = l >> 4, lo = l & 15;
    if (grp < 20) {
        int kk = grp >> 2, jt = grp & 3;
#pragma unroll
        for (int e2 = 0; e2 < 8; e2++) {
            int k = kk * 32 + hi * 8 + e2, j = jt * 16 + lo;
            W1f[(size_t)(grp * 64 + l) * 8 + e2] = (k < 137) ? f2bf(W1[k * 64 + j]) : (u16)0;
        }
    } else if (grp < 28) {
        int g = grp - 20; int kk = g >> 2, jt = g & 3;
#pragma unroll
        for (int e2 = 0; e2 < 8; e2++) {
            int k = kk * 32 + hi * 8 + e2, j = jt * 16 + lo;
            W2f[(size_t)(g * 64 + l) * 8 + e2] = f2bf(W2[k * 64 + j]);
        }
    } else {
        int g = grp - 28; int kk = g >> 4, jt = g & 15;
#pragma unroll
        for (int e2 = 0; e2 < 8; e2++) {
            int k = kk * 32 + hi * 8 + e2, j = jt * 16 + lo;
            W3f[(size_t)(g * 64 + l) * 8 + e2] = f2bf(W3[k * 256 + j]);
        }
    }
}

// ---- node precompute: ns = s@Wsc (bf16), s_up = s@Wup0, v_up = einsum(v,Wup1) ----
__global__ void node_prep_kernel(const float* __restrict__ node_feats,
                                 const float* __restrict__ Wsc, const float* __restrict__ Wup0,
                                 const float* __restrict__ Wup1,
                                 u16* __restrict__ ns_bf, float* __restrict__ s_up,
                                 float* __restrict__ v_up) {
    __shared__ float nf[4][256];
    int tid = threadIdx.x;
    int wv = tid >> 6, l = tid & 63;
    int n = blockIdx.x * 4 + wv;
    *(float4*)&nf[wv][l * 4] = *(const float4*)(node_feats + (size_t)n * 256 + l * 4);
    __syncthreads();
    float a_ns = 0.f, a_su = 0.f, av0 = 0.f, av1 = 0.f, av2 = 0.f;
    for (int c = 0; c < 64; c++) {
        float sc = nf[wv][c];
        a_ns = fmaf(sc, Wsc[c * 64 + l], a_ns);
        a_su = fmaf(sc, Wup0[c * 64 + l], a_su);
        float wu = Wup1[c * 64 + l];
        av0 = fmaf(nf[wv][64 + c * 3 + 0], wu, av0);
        av1 = fmaf(nf[wv][64 + c * 3 + 1], wu, av1);
        av2 = fmaf(nf[wv][64 + c * 3 + 2], wu, av2);
    }
    ns_bf[(size_t)n * 64 + l] = f2bf(a_ns);
    s_up[(size_t)n * 64 + l] = a_su;
    v_up[(size_t)n * 192 + l * 3 + 0] = av0;
    v_up[(size_t)n * 192 + l * 3 + 1] = av1;
    v_up[(size_t)n * 192 + l * 3 + 2] = av2;
}

// ---- counting sort by rcv ----
__global__ void hist_kernel(const int* __restrict__ ei, int* __restrict__ cnt) {
    int e = blockIdx.x * 256 + threadIdx.x;
    if (e < N_EDGES) atomicAdd(&cnt[ei[N_EDGES + e]], 1);
}

__global__ void scan_kernel(const int* __restrict__ cnt, int* __restrict__ offs,
                            int* __restrict__ cursor) {
    __shared__ int buf[1024];
    __shared__ int runs;
    int t = threadIdx.x;
    if (t == 0) runs = 0;
    __syncthreads();
    for (int base = 0; base < N_NODES; base += 1024) {
        int i = base + t;
        int v = (i < N_NODES) ? cnt[i] : 0;
        buf[t] = v;
        __syncthreads();
        for (int d = 1; d < 1024; d <<= 1) {
            int add = (t >= d) ? buf[t - d] : 0;
            __syncthreads();
            buf[t] += add;
            __syncthreads();
        }
        int excl = buf[t] - v;
        int base_run = runs;
        if (i < N_NODES) { offs[i] = base_run + excl; cursor[i] = base_run + excl; }
        __syncthreads();
        if (t == 1023) runs += buf[1023];
        __syncthreads();
    }
    if (t == 0) offs[N_NODES] = runs;
}

__global__ void scatter_kernel(const int* __restrict__ ei, int* __restrict__ cursor,
                               int* __restrict__ esort) {
    int e = blockIdx.x * 256 + threadIdx.x;
    if (e < N_EDGES) {
        int rc = ei[N_EDGES + e];
        int pos = atomicAdd(&cursor[rc], 1);
        esort[pos] = e;
    }
}

// ---- main fused kernel: 8 nodes/block, edge MLP via bf16 MFMA, LDS segment-sum, epilogue ----
__global__ __launch_bounds__(256, 2) void main_kernel(
    const u16* __restrict__ ns_bf, const float* __restrict__ s_up, const float* __restrict__ v_up,
    const u16* __restrict__ W1f, const u16* __restrict__ W2f, const u16* __restrict__ W3f,
    const float* __restrict__ b1, const float* __restrict__ b2,
    const float* __restrict__ Ws, const float* __restrict__ Wv,
    const float* __restrict__ edge_attrs, const float* __restrict__ edge_feats,
    const float* __restrict__ lengths, const int* __restrict__ ei,
    const int* __restrict__ offs, const int* __restrict__ esort,
    float* __restrict__ out) {

    __shared__ u16 mlp[64][168];     // gathered mlp_in, bf16, K padded to 160 (+8 pad)
    __shared__ u16 h1s[64][72];
    __shared__ u16 h2s[64][72];
    __shared__ float m0s[8][129];    // [node][128] (+1 pad)
    __shared__ float m1s[8][387];    // [node][128*3] (+3 pad)
    __shared__ float y0s[64];
    __shared__ float y1s[64][3];
    __shared__ int snds[64];
    __shared__ int nlocs[64];

    const int tid = threadIdx.x;
    const int l = tid & 63;
    const int lo16 = l & 15;
    const int hi = l >> 4;
    const int w = tid >> 6;
    const int erow = (w << 4) | lo16;   // A-fragment row (edge slot)
    const int koff = hi * 8;
    const int drow = (w << 4) + hi * 4; // D base row (edge slot)

    const short8* w1frag = (const short8*)W1f;
    const short8* w2frag = (const short8*)W2f;
    const short8* w3frag = (const short8*)W3f;

    float bb1[4], bb2[4];
#pragma unroll
    for (int jt = 0; jt < 4; jt++) { bb1[jt] = b1[jt * 16 + lo16]; bb2[jt] = b2[jt * 16 + lo16]; }

    const int nb = blockIdx.x * 8;
    const int estart = offs[nb];
    const int eend = offs[nb + 8];

    // one-time LDS init: m accumulators + mlp zero-pad region (k 136..167)
    for (int i = tid; i < 8 * 129; i += 256) (&m0s[0][0])[i] = 0.f;
    for (int i = tid; i < 8 * 387; i += 256) (&m1s[0][0])[i] = 0.f;
    {
        int rr = tid >> 2, pp = tid & 3;
        uint4 z = {0, 0, 0, 0};
        *(uint4*)&mlp[rr][136 + pp * 8] = z;
    }

    for (int tb = estart; tb < eend; tb += 64) {
        int tcnt = eend - tb; if (tcnt > 64) tcnt = 64;
        __syncthreads();  // init done / previous tile's p-phase & layer reads done

        // ---- stage gathered edge inputs ----
        {
            int es = tid >> 2, part = tid & 3;
            if (es < tcnt) {
                int e = esort[tb + es];
                int sn = ei[e];
                int rc = ei[N_EDGES + e];
                const uint4* ps = (const uint4*)(ns_bf + (size_t)sn * 64 + part * 16);
                uint4 s0 = ps[0], s1 = ps[1];
                *(uint4*)&mlp[es][part * 16] = s0;
                *(uint4*)&mlp[es][part * 16 + 8] = s1;
                const uint4* pr = (const uint4*)(ns_bf + (size_t)rc * 64 + part * 16);
                uint4 r0v = pr[0], r1v = pr[1];
                *(uint4*)&mlp[es][64 + part * 16] = r0v;
                *(uint4*)&mlp[es][64 + part * 16 + 8] = r1v;
                if (part == 0) {
                    float4 f0 = *(const float4*)(edge_feats + (size_t)e * 8);
                    float4 f1 = *(const float4*)(edge_feats + (size_t)e * 8 + 4);
                    u32 pk0 = (u32)f2bf(f0.x) | ((u32)f2bf(f0.y) << 16);
                    u32 pk1 = (u32)f2bf(f0.z) | ((u32)f2bf(f0.w) << 16);
                    u32 pk2 = (u32)f2bf(f1.x) | ((u32)f2bf(f1.y) << 16);
                    u32 pk3 = (u32)f2bf(f1.z) | ((u32)f2bf(f1.w) << 16);
                    uint4 pk = {pk0, pk1, pk2, pk3};
                    *(uint4*)&mlp[es][128] = pk;
                    mlp[es][136] = f2bf(lengths[e]);
                    float4 ea = *(const float4*)(edge_attrs + (size_t)e * 4);
                    y0s[es] = ea.x; y1s[es][0] = ea.y; y1s[es][1] = ea.z; y1s[es][2] = ea.w;
                    snds[es] = sn; nlocs[es] = rc - nb;
                }
            }
        }
        __syncthreads();

        // ---- layer 1: (64x160) @ (160x64), bf16 MFMA ----
        f32x4 a1c[4];
#pragma unroll
        for (int jt = 0; jt < 4; jt++) a1c[jt] = (f32x4)(0.0f);
#pragma unroll
        for (int kk = 0; kk < 5; kk++) {
            short8 af = *(const short8*)&mlp[erow][kk * 32 + koff];
            const short8* wb = w1frag + kk * 256 + l;
            a1c[0] = mfma16(af, wb[0],   a1c[0]);
            a1c[1] = mfma16(af, wb[64],  a1c[1]);
            a1c[2] = mfma16(af, wb[128], a1c[2]);
            a1c[3] = mfma16(af, wb[192], a1c[3]);
        }
#pragma unroll
        for (int jt = 0; jt < 4; jt++) {
#pragma unroll
            for (int r = 0; r < 4; r++) {
                float x = a1c[jt][r] + bb1[jt];
                h1s[drow + r][jt * 16 + lo16] = f2bf(silu(x));
            }
        }
        __syncthreads();

        // ---- layer 2: (64x64) @ (64x64) ----
        f32x4 a2c[4];
#pragma unroll
        for (int jt = 0; jt < 4; jt++) a2c[jt] = (f32x4)(0.0f);
#pragma unroll
        for (int kk = 0; kk < 2; kk++) {
            short8 af = *(const short8*)&h1s[erow][kk * 32 + koff];
            const short8* wb = w2frag + kk * 256 + l;
            a2c[0] = mfma16(af, wb[0],   a2c[0]);
            a2c[1] = mfma16(af, wb[64],  a2c[1]);
            a2c[2] = mfma16(af, wb[128], a2c[2]);
            a2c[3] = mfma16(af, wb[192], a2c[3]);
        }
#pragma unroll
        for (int jt = 0; jt < 4; jt++) {
#pragma unroll
            for (int r = 0; r < 4; r++) {
                float x = a2c[jt][r] + bb2[jt];
                h2s[drow + r][jt * 16 + lo16] = f2bf(silu(x));
            }
        }
        __syncthreads();

        // ---- layer 3: (64x64) @ (64x256) -> tw ----
        f32x4 tw[16];
#pragma unroll
        for (int jt = 0; jt < 16; jt++) tw[jt] = (f32x4)(0.0f);
#pragma unroll
        for (int kk = 0; kk < 2; kk++) {
            short8 af = *(const short8*)&h2s[erow][kk * 32 + koff];
            const short8* wb = w3frag + kk * 1024 + l;
#pragma unroll
            for (int jt = 0; jt < 16; jt++) tw[jt] = mfma16(af, wb[jt * 64], tw[jt]);
        }

        // ---- p-phase: tensor products + LDS segment accumulation ----
        {
            int r0 = drow;
            int nv = tcnt - r0; if (nv > 4) nv = 4;
            if (nv > 0) {
                float y0v[4], y11[4], y12[4], y13[4];
                int snv[4], nlv[4];
#pragma unroll
                for (int r = 0; r < 4; r++) {
                    int rr = (r < nv) ? (r0 + r) : r0;
                    y0v[r] = y0s[rr]; y11[r] = y1s[rr][0]; y12[r] = y1s[rr][1]; y13[r] = y1s[rr][2];
                    snv[r] = snds[rr]; nlv[r] = nlocs[rr];
                }
                bool uni = (nv == 4) && (nlv[0] == nlv[3]);
#pragma unroll
                for (int jt = 0; jt < 4; jt++) {
                    int c = jt * 16 + lo16;
                    float xsv[4], xa[4], xb[4], xc[4];
#pragma unroll
                    for (int r = 0; r < 4; r++) {
                        if (r < nv) {
                            xsv[r] = s_up[(size_t)snv[r] * 64 + c];
                            const float* vp = v_up + (size_t)snv[r] * 192 + c * 3;
                            xa[r] = vp[0]; xb[r] = vp[1]; xc[r] = vp[2];
                        } else { xsv[r] = 0.f; xa[r] = 0.f; xb[r] = 0.f; xc[r] = 0.f; }
                    }
                    if (uni) {
                        float a0 = 0, a1 = 0, q20 = 0, q21 = 0, q22 = 0, q30 = 0, q31 = 0, q32 = 0;
#pragma unroll
                        for (int r = 0; r < 4; r++) {
                            float w0v = tw[jt][r], w1v = tw[4 + jt][r];
                            float w2v = tw[8 + jt][r], w3v = tw[12 + jt][r];
                            float dv = xa[r] * y11[r] + xb[r] * y12[r] + xc[r] * y13[r];
                            a0 += xsv[r] * y0v[r] * w0v;
                            a1 += dv * w1v;
                            float sw2 = xsv[r] * w2v;
                            q20 += sw2 * y11[r]; q21 += sw2 * y12[r]; q22 += sw2 * y13[r];
                            float yw3 = y0v[r] * w3v;
                            q30 += xa[r] * yw3; q31 += xb[r] * yw3; q32 += xc[r] * yw3;
                        }
                        int nl = nlv[0];
                        atomicAdd(&m0s[nl][c], a0);
                        atomicAdd(&m0s[nl][64 + c], a1 * INV_SQRT3);
                        atomicAdd(&m1s[nl][c * 3 + 0], q20);
                        atomicAdd(&m1s[nl][c * 3 + 1], q21);
                        atomicAdd(&m1s[nl][c * 3 + 2], q22);
                        atomicAdd(&m1s[nl][(64 + c) * 3 + 0], q30);
                        atomicAdd(&m1s[nl][(64 + c) * 3 + 1], q31);
                        atomicAdd(&m1s[nl][(64 + c) * 3 + 2], q32);
                    } else {
#pragma unroll
                        for (int r = 0; r < 4; r++) {
                            if (r < nv) {
                                float w0v = tw[jt][r], w1v = tw[4 + jt][r];
                                float w2v = tw[8 + jt][r], w3v = tw[12 + jt][r];
                                int nl = nlv[r];
                                float dv = xa[r] * y11[r] + xb[r] * y12[r] + xc[r] * y13[r];
                                atomicAdd(&m0s[nl][c], xsv[r] * y0v[r] * w0v);
                                atomicAdd(&m0s[nl][64 + c], dv * w1v * INV_SQRT3);
                                float sw2 = xsv[r] * w2v;
                                atomicAdd(&m1s[nl][c * 3 + 0], sw2 * y11[r]);
                                atomicAdd(&m1s[nl][c * 3 + 1], sw2 * y12[r]);
                                atomicAdd(&m1s[nl][c * 3 + 2], sw2 * y13[r]);
                                float yw3 = y0v[r] * w3v;
                                atomicAdd(&m1s[nl][(64 + c) * 3 + 0], xa[r] * yw3);
                                atomicAdd(&m1s[nl][(64 + c) * 3 + 1], xb[r] * yw3);
                                atomicAdd(&m1s[nl][(64 + c) * 3 + 2], xc[r] * yw3);
                            }
                        }
                    }
                }
            }
        }
    }

    __syncthreads();

    // ---- epilogue: out_s = m0@Ws/16 ; out_v = einsum(m1,Wv)/16 ----
    {
        int ln = tid >> 5;
        int db = (tid & 31) * 2;
#pragma unroll
        for (int dd = 0; dd < 2; dd++) {
            int d = db + dd;
            float as = 0.f, av0 = 0.f, av1 = 0.f, av2 = 0.f;
            for (int c = 0; c < 128; c++) {
                float wsv = Ws[c * 64 + d];
                float wvv = Wv[c * 64 + d];
                as  = fmaf(m0s[ln][c], wsv, as);
                av0 = fmaf(m1s[ln][c * 3 + 0], wvv, av0);
                av1 = fmaf(m1s[ln][c * 3 + 1], wvv, av1);
                av2 = fmaf(m1s[ln][c * 3 + 2], wvv, av2);
            }
            int n = nb + ln;
            float4 o = {as * 0.0625f, av0 * 0.0625f, av1 * 0.0625f, av2 * 0.0625f};
            *(float4*)(out + (size_t)n * 256 + d * 4) = o;
        }
    }
}

extern "C" void kernel_launch(void* const* d_in, const int* in_sizes, int n_in,
                              void* d_out, int out_size, void* d_ws, size_t ws_size,
                              hipStream_t stream) {
    (void)in_sizes; (void)n_in; (void)out_size; (void)ws_size;
    const float* node_feats = (const float*)d_in[0];
    const float* edge_attrs = (const float*)d_in[1];
    const float* edge_feats = (const float*)d_in[2];
    const float* lengths    = (const float*)d_in[3];
    const int*   edge_index = (const int*)d_in[4];
    const float* Wsc  = (const float*)d_in[5];
    const float* Wup0 = (const float*)d_in[6];
    const float* Wup1 = (const float*)d_in[7];
    const float* W1   = (const float*)d_in[8];
    const float* b1   = (const float*)d_in[9];
    const float* W2   = (const float*)d_in[10];
    const float* b2   = (const float*)d_in[11];
    const float* W3   = (const float*)d_in[12];
    const float* Ws   = (const float*)d_in[13];
    const float* Wv   = (const float*)d_in[14];

    char* ws = (char*)d_ws;
    u16*   ns_bf  = (u16*)(ws + OFF_NSBF);
    float* s_up   = (float*)(ws + OFF_SUP);
    float* v_up   = (float*)(ws + OFF_VUP);
    u16*   W1f    = (u16*)(ws + OFF_W1F);
    u16*   W2f    = (u16*)(ws + OFF_W2F);
    u16*   W3f    = (u16*)(ws + OFF_W3F);
    int*   cnt    = (int*)(ws + OFF_CNT);
    int*   offs   = (int*)(ws + OFF_OFFS);
    int*   cursor = (int*)(ws + OFF_CUR);
    int*   esort  = (int*)(ws + OFF_SORT);
    float* out    = (float*)d_out;

    hipMemsetAsync(cnt, 0, N_NODES * sizeof(int), stream);
    prep_w_kernel<<<15, 256, 0, stream>>>(W1, W2, W3, W1f, W2f, W3f);
    node_prep_kernel<<<N_NODES / 4, 256, 0, stream>>>(node_feats, Wsc, Wup0, Wup1,
                                                      ns_bf, s_up, v_up);
    hist_kernel<<<N_EDGES / 256, 256, 0, stream>>>(edge_index, cnt);
    scan_kernel<<<1, 1024, 0, stream>>>(cnt, offs, cursor);
    scatter_kernel<<<N_EDGES / 256, 256, 0, stream>>>(edge_index, cursor, esort);
    main_kernel<<<N_NODES / 8, 256, 0, stream>>>(ns_bf, s_up, v_up, W1f, W2f, W3f,
                                                 b1, b2, Ws, Wv,
                                                 edge_attrs, edge_feats, lengths, edge_index,
                                                 offs, esort, out);
}

// Round 2
// 636.853 us; speedup vs baseline: 1.2576x; 1.2576x over previous
//
#include <hip/hip_runtime.h>

#define N_NODES 20000
#define N_EDGES 320000
#define INV_SQRT3 0.5773502691896258f
#define NCHUNK 4
#define NPC 5000            // nodes per chunk
#define EDGE_CAP 84032      // max edges per chunk (mean 80000, sigma ~245)
#define K3_BLOCKS (EDGE_CAP / 64)

typedef unsigned short u16;
typedef unsigned int u32;
typedef __attribute__((ext_vector_type(8))) short short8;
typedef __attribute__((ext_vector_type(4))) float f32x4;
typedef __attribute__((ext_vector_type(4))) u32 u32x4v;

// ---- workspace layout (bytes) ----
static const size_t OFF_NSBF = 0;            // N*64 bf16
static const size_t OFF_SV   = 2560000;      // N*64 float4 (s, v0, v1, v2)
static const size_t OFF_MG   = 23040000;     // N*512 f32
static const size_t OFF_TW   = 64000000;     // EDGE_CAP*256 fp16
static const size_t OFF_W1F  = 107024384;
static const size_t OFF_W2F  = 107044864;
static const size_t OFF_W3F  = 107053056;
static const size_t OFF_CNT  = 107085824;
static const size_t OFF_OFFS = 107165824;
static const size_t OFF_CUR  = 107245888;
static const size_t OFF_ES   = 107325888;
static const size_t OFF_SS   = 108605888;
static const size_t OFF_RS   = 109885888;    // ends ~111.2MB

static __device__ __forceinline__ u16 f2bf(float x) {
    union { float f; u32 u; } c; c.f = x;
    u32 u = c.u + 0x7fffu + ((c.u >> 16) & 1u);
    return (u16)(u >> 16);
}
static __device__ __forceinline__ u16 f2h(float x) {
    union { _Float16 h; u16 u; } c; c.h = (_Float16)x; return c.u;
}
static __device__ __forceinline__ float h2f(u32 b) {
    union { u16 u; _Float16 h; } c; c.u = (u16)b; return (float)c.h;
}
static __device__ __forceinline__ f32x4 mfma16(short8 a, short8 b, f32x4 c) {
    return __builtin_amdgcn_mfma_f32_16x16x32_bf16(a, b, c, 0, 0, 0);
}
static __device__ __forceinline__ float silu(float x) {
    return x / (1.0f + __expf(-x));
}
template <typename T>
static __device__ __forceinline__ T ntload(const T* p) { return __builtin_nontemporal_load(p); }
template <typename T>
static __device__ __forceinline__ void ntstore(T* p, T v) { __builtin_nontemporal_store(v, p); }

// ---- prep: weights -> MFMA B-fragment order (bf16) ----
__global__ void prep_w_kernel(const float* __restrict__ W1, const float* __restrict__ W2,
                              const float* __restrict__ W3,
                              u16* __restrict__ W1f, u16* __restrict__ W2f, u16* __restrict__ W3f) {
    int t = blockIdx.x * 256 + threadIdx.x;
    if (t >= 3840) return;
    int l = t & 63, grp = t >> 6;
    int hi = l >> 4, lo = l & 15;
    if (grp < 20) {
        int kk = grp >> 2, jt = grp & 3;
#pragma unroll
        for (int e2 = 0; e2 < 8; e2++) {
            int k = kk * 32 + hi * 8 + e2, j = jt * 16 + lo;
            W1f[(size_t)(grp * 64 + l) * 8 + e2] = (k < 137) ? f2bf(W1[k * 64 + j]) : (u16)0;
        }
    } else if (grp < 28) {
        int g = grp - 20; int kk = g >> 2, jt = g & 3;
#pragma unroll
        for (int e2 = 0; e2 < 8; e2++) {
            int k = kk * 32 + hi * 8 + e2, j = jt * 16 + lo;
            W2f[(size_t)(g * 64 + l) * 8 + e2] = f2bf(W2[k * 64 + j]);
        }
    } else {
        int g = grp - 28; int kk = g >> 4, jt = g & 15;
#pragma unroll
        for (int e2 = 0; e2 < 8; e2++) {
            int k = kk * 32 + hi * 8 + e2, j = jt * 16 + lo;
            W3f[(size_t)(g * 64 + l) * 8 + e2] = f2bf(W3[k * 256 + j]);
        }
    }
}

// ---- node precompute: ns = s@Wsc (bf16), sv[n][c] = {s_up, v_up0, v_up1, v_up2} ----
__global__ void node_prep_kernel(const float* __restrict__ node_feats,
                                 const float* __restrict__ Wsc, const float* __restrict__ Wup0,
                                 const float* __restrict__ Wup1,
                                 u16* __restrict__ ns_bf, f32x4* __restrict__ sv) {
    __shared__ float nf[4][256];
    int tid = threadIdx.x;
    int wv = tid >> 6, l = tid & 63;
    int n = blockIdx.x * 4 + wv;
    *(float4*)&nf[wv][l * 4] = *(const float4*)(node_feats + (size_t)n * 256 + l * 4);
    __syncthreads();
    float a_ns = 0.f, a_su = 0.f, av0 = 0.f, av1 = 0.f, av2 = 0.f;
    for (int c = 0; c < 64; c++) {
        float sc = nf[wv][c];
        a_ns = fmaf(sc, Wsc[c * 64 + l], a_ns);
        a_su = fmaf(sc, Wup0[c * 64 + l], a_su);
        float wu = Wup1[c * 64 + l];
        av0 = fmaf(nf[wv][64 + c * 3 + 0], wu, av0);
        av1 = fmaf(nf[wv][64 + c * 3 + 1], wu, av1);
        av2 = fmaf(nf[wv][64 + c * 3 + 2], wu, av2);
    }
    ns_bf[(size_t)n * 64 + l] = f2bf(a_ns);
    f32x4 o; o.x = a_su; o.y = av0; o.z = av1; o.w = av2;
    sv[(size_t)n * 64 + l] = o;
}

// ---- counting sort by rcv ----
__global__ void hist_kernel(const int* __restrict__ ei, int* __restrict__ cnt) {
    int e = blockIdx.x * 256 + threadIdx.x;
    if (e < N_EDGES) atomicAdd(&cnt[ei[N_EDGES + e]], 1);
}

__global__ void scan_kernel(const int* __restrict__ cnt, int* __restrict__ offs,
                            int* __restrict__ cursor) {
    __shared__ int buf[1024];
    int t = threadIdx.x;
    int base = t * 20;
    int loc[20];
    int tot = 0;
#pragma unroll
    for (int i = 0; i < 20; i++) {
        int idx = base + i;
        int v = (idx < N_NODES) ? cnt[idx] : 0;
        loc[i] = tot;
        tot += v;
    }
    buf[t] = tot;
    __syncthreads();
    for (int d = 1; d < 1024; d <<= 1) {
        int add = (t >= d) ? buf[t - d] : 0;
        __syncthreads();
        buf[t] += add;
        __syncthreads();
    }
    int ebase = buf[t] - tot;
#pragma unroll
    for (int i = 0; i < 20; i++) {
        int idx = base + i;
        if (idx < N_NODES) { int o = ebase + loc[i]; offs[idx] = o; cursor[idx] = o; }
    }
    if (t == 1023) offs[N_NODES] = buf[1023];
}

__global__ void scatter_kernel(const int* __restrict__ ei, int* __restrict__ cursor,
                               int* __restrict__ esort, int* __restrict__ ssort,
                               int* __restrict__ rsort) {
    int e = blockIdx.x * 256 + threadIdx.x;
    if (e < N_EDGES) {
        int sn = ei[e];
        int rc = ei[N_EDGES + e];
        int pos = atomicAdd(&cursor[rc], 1);
        esort[pos] = e;
        ssort[pos] = sn;
        rsort[pos] = rc;
    }
}

// ---- K3: edge MLP over sorted edges, bf16 MFMA, tw -> fp16 (NT) ----
__global__ __launch_bounds__(256, 4) void mlp_kernel(
    const u16* __restrict__ ns_bf,
    const u16* __restrict__ W1f, const u16* __restrict__ W2f, const u16* __restrict__ W3f,
    const float* __restrict__ b1, const float* __restrict__ b2,
    const float* __restrict__ edge_feats, const float* __restrict__ lengths,
    const int* __restrict__ esort, const int* __restrict__ ssort, const int* __restrict__ rsort,
    const int* __restrict__ offs, u16* __restrict__ twg, int n0) {

    __shared__ u16 mlp[64][168];
    __shared__ u16 h1s[64][72];
    __shared__ u16 h2s[64][72];

    const int tid = threadIdx.x;
    const int l = tid & 63;
    const int lo16 = l & 15;
    const int hi = l >> 4;
    const int w = tid >> 6;
    const int erow = (w << 4) | lo16;
    const int koff = hi * 8;
    const int drow = (w << 4) + hi * 4;

    const int cb = offs[n0];
    const int ce = offs[n0 + NPC];
    const int p0 = cb + blockIdx.x * 64;
    if (p0 >= ce) return;
    int tcnt = ce - p0; if (tcnt > 64) tcnt = 64;

    const short8* w1frag = (const short8*)W1f;
    const short8* w2frag = (const short8*)W2f;
    const short8* w3frag = (const short8*)W3f;

    float bb1[4], bb2[4];
#pragma unroll
    for (int jt = 0; jt < 4; jt++) { bb1[jt] = b1[jt * 16 + lo16]; bb2[jt] = b2[jt * 16 + lo16]; }

    // zero pad region k=136..167 (K rows 137..159 of W1f are zero, but NaN*0=NaN)
    {
        int rr = tid >> 2, pp = tid & 3;
        uint4 z = {0, 0, 0, 0};
        *(uint4*)&mlp[rr][136 + pp * 8] = z;
    }

    // stage gathered edge inputs
    {
        int es = tid >> 2, part = tid & 3;
        if (es < tcnt) {
            int e = esort[p0 + es];
            int sn = ssort[p0 + es];
            int rc = rsort[p0 + es];
            const uint4* ps = (const uint4*)(ns_bf + (size_t)sn * 64 + part * 16);
            uint4 s0 = ps[0], s1 = ps[1];
            *(uint4*)&mlp[es][part * 16] = s0;
            *(uint4*)&mlp[es][part * 16 + 8] = s1;
            const uint4* pr = (const uint4*)(ns_bf + (size_t)rc * 64 + part * 16);
            uint4 r0v = pr[0], r1v = pr[1];
            *(uint4*)&mlp[es][64 + part * 16] = r0v;
            *(uint4*)&mlp[es][64 + part * 16 + 8] = r1v;
            if (part == 0) {
                float4 f0 = *(const float4*)(edge_feats + (size_t)e * 8);
                float4 f1 = *(const float4*)(edge_feats + (size_t)e * 8 + 4);
                u32 pk0 = (u32)f2bf(f0.x) | ((u32)f2bf(f0.y) << 16);
                u32 pk1 = (u32)f2bf(f0.z) | ((u32)f2bf(f0.w) << 16);
                u32 pk2 = (u32)f2bf(f1.x) | ((u32)f2bf(f1.y) << 16);
                u32 pk3 = (u32)f2bf(f1.z) | ((u32)f2bf(f1.w) << 16);
                uint4 pk = {pk0, pk1, pk2, pk3};
                *(uint4*)&mlp[es][128] = pk;
                mlp[es][136] = f2bf(lengths[e]);
            }
        }
    }
    __syncthreads();

    // layer 1: (64x160) @ (160x64)
    f32x4 a1c[4];
#pragma unroll
    for (int jt = 0; jt < 4; jt++) a1c[jt] = (f32x4)(0.0f);
#pragma unroll
    for (int kk = 0; kk < 5; kk++) {
        short8 af = *(const short8*)&mlp[erow][kk * 32 + koff];
        const short8* wb = w1frag + kk * 256 + l;
        a1c[0] = mfma16(af, wb[0],   a1c[0]);
        a1c[1] = mfma16(af, wb[64],  a1c[1]);
        a1c[2] = mfma16(af, wb[128], a1c[2]);
        a1c[3] = mfma16(af, wb[192], a1c[3]);
    }
#pragma unroll
    for (int jt = 0; jt < 4; jt++) {
#pragma unroll
        for (int r = 0; r < 4; r++) {
            float x = a1c[jt][r] + bb1[jt];
            h1s[drow + r][jt * 16 + lo16] = f2bf(silu(x));
        }
    }
    __syncthreads();

    // layer 2: (64x64) @ (64x64)
    f32x4 a2c[4];
#pragma unroll
    for (int jt = 0; jt < 4; jt++) a2c[jt] = (f32x4)(0.0f);
#pragma unroll
    for (int kk = 0; kk < 2; kk++) {
        short8 af = *(const short8*)&h1s[erow][kk * 32 + koff];
        const short8* wb = w2frag + kk * 256 + l;
        a2c[0] = mfma16(af, wb[0],   a2c[0]);
        a2c[1] = mfma16(af, wb[64],  a2c[1]);
        a2c[2] = mfma16(af, wb[128], a2c[2]);
        a2c[3] = mfma16(af, wb[192], a2c[3]);
    }
#pragma unroll
    for (int jt = 0; jt < 4; jt++) {
#pragma unroll
        for (int r = 0; r < 4; r++) {
            float x = a2c[jt][r] + bb2[jt];
            h2s[drow + r][jt * 16 + lo16] = f2bf(silu(x));
        }
    }
    __syncthreads();

    // layer 3: (64x64) @ (64x256)
    f32x4 tw[16];
#pragma unroll
    for (int jt = 0; jt < 16; jt++) tw[jt] = (f32x4)(0.0f);
#pragma unroll
    for (int kk = 0; kk < 2; kk++) {
        short8 af = *(const short8*)&h2s[erow][kk * 32 + koff];
        const short8* wb = w3frag + kk * 1024 + l;
#pragma unroll
        for (int jt = 0; jt < 16; jt++) tw[jt] = mfma16(af, wb[jt * 64], tw[jt]);
    }

    // store tw as fp16: layout per edge: [lo16][k=q*4+j3]  (16 fp16 = 32B per lo16)
    int relrow = blockIdx.x * 64 + drow;
#pragma unroll
    for (int r = 0; r < 4; r++) {
        if (drow + r < tcnt) {
            u32 q0a = (u32)f2h(tw[0][r])  | ((u32)f2h(tw[1][r])  << 16);
            u32 q0b = (u32)f2h(tw[2][r])  | ((u32)f2h(tw[3][r])  << 16);
            u32 q1a = (u32)f2h(tw[4][r])  | ((u32)f2h(tw[5][r])  << 16);
            u32 q1b = (u32)f2h(tw[6][r])  | ((u32)f2h(tw[7][r])  << 16);
            u32 q2a = (u32)f2h(tw[8][r])  | ((u32)f2h(tw[9][r])  << 16);
            u32 q2b = (u32)f2h(tw[10][r]) | ((u32)f2h(tw[11][r]) << 16);
            u32 q3a = (u32)f2h(tw[12][r]) | ((u32)f2h(tw[13][r]) << 16);
            u32 q3b = (u32)f2h(tw[14][r]) | ((u32)f2h(tw[15][r]) << 16);
            u16* dst = twg + (size_t)(relrow + r) * 256 + lo16 * 16;
            u32x4v A = {q0a, q0b, q1a, q1b};
            u32x4v B = {q2a, q2b, q3a, q3b};
            ntstore((u32x4v*)dst, A);
            ntstore(((u32x4v*)dst) + 1, B);
        }
    }
}

// ---- K4: one wave per node; tensor products + register segment-sum ----
__global__ __launch_bounds__(256, 4) void seg_kernel(
    const f32x4* __restrict__ sv, const float* __restrict__ edge_attrs,
    const int* __restrict__ esort, const int* __restrict__ ssort,
    const int* __restrict__ offs, const u16* __restrict__ twg,
    float* __restrict__ m_g, int n0) {
    const int lane = threadIdx.x & 63;
    const int wv = threadIdx.x >> 6;
    const int n = n0 + blockIdx.x * 4 + wv;
    const int c = lane;
    const int jt = c >> 4, lo16 = c & 15;
    const int cb = offs[n0];
    const int e0 = offs[n], e1 = offs[n + 1];
    float a_m0 = 0.f, a_m0b = 0.f;
    float a20 = 0.f, a21 = 0.f, a22 = 0.f, a30 = 0.f, a31 = 0.f, a32 = 0.f;
#pragma unroll 2
    for (int pos = e0; pos < e1; ++pos) {
        int e = esort[pos];
        int sn = ssort[pos];
        const u16* twp = twg + (size_t)(pos - cb) * 256 + lo16 * 16;
        u32x4v ta = ntload((const u32x4v*)twp);
        u32x4v tb = ntload(((const u32x4v*)twp) + 1);
        f32x4 y4 = *(const f32x4*)(edge_attrs + (size_t)e * 4);
        f32x4 s4 = sv[(size_t)sn * 64 + c];
        u32 wwa = (jt & 2) ? ta.y : ta.x;
        u32 wwb = (jt & 2) ? ta.w : ta.z;
        u32 wwc = (jt & 2) ? tb.y : tb.x;
        u32 wwd = (jt & 2) ? tb.w : tb.z;
        int sh = (jt & 1) << 4;
        float w0 = h2f((wwa >> sh) & 0xffffu);
        float w1 = h2f((wwb >> sh) & 0xffffu);
        float w2 = h2f((wwc >> sh) & 0xffffu);
        float w3 = h2f((wwd >> sh) & 0xffffu);
        float xs = s4.x, xv0 = s4.y, xv1 = s4.z, xv2 = s4.w;
        float y0 = y4.x, ya = y4.y, yb = y4.z, yc = y4.w;
        a_m0 = fmaf(xs * y0, w0, a_m0);
        float dv = xv0 * ya + xv1 * yb + xv2 * yc;
        a_m0b = fmaf(dv, w1, a_m0b);
        float sw2 = xs * w2;
        a20 = fmaf(sw2, ya, a20); a21 = fmaf(sw2, yb, a21); a22 = fmaf(sw2, yc, a22);
        float yw3 = y0 * w3;
        a30 = fmaf(xv0, yw3, a30); a31 = fmaf(xv1, yw3, a31); a32 = fmaf(xv2, yw3, a32);
    }
    float* mr = m_g + (size_t)n * 512;
    ntstore(mr + c,        a_m0);
    ntstore(mr + 64 + c,   a_m0b * INV_SQRT3);
    ntstore(mr + 128 + c,  a20);
    ntstore(mr + 192 + c,  a30);
    ntstore(mr + 256 + c,  a21);
    ntstore(mr + 320 + c,  a31);
    ntstore(mr + 384 + c,  a22);
    ntstore(mr + 448 + c,  a32);
}

// ---- K5: per-node output transform, Ws/Wv staged in LDS ----
__global__ __launch_bounds__(256, 2) void out_kernel(
    const float* __restrict__ m_g, const float* __restrict__ Ws, const float* __restrict__ Wv,
    float* __restrict__ out) {
    __shared__ float WL[16384];
    const int tid = threadIdx.x;
    for (int i = tid; i < 2048; i += 256) ((float4*)WL)[i] = ((const float4*)Ws)[i];
    for (int i = tid; i < 2048; i += 256) ((float4*)WL)[2048 + i] = ((const float4*)Wv)[i];
    __syncthreads();
    const int d = tid >> 2, part = tid & 3;
    const float* w = WL + (part ? 8192 : 0);
    int nstart = blockIdx.x * 40;
    int nend = nstart + 40; if (nend > N_NODES) nend = N_NODES;
    for (int n = nstart; n < nend; ++n) {
        const float* mrow = m_g + (size_t)n * 512 + part * 128;
        float acc = 0.f;
#pragma unroll 4
        for (int cc = 0; cc < 128; cc++) acc = fmaf(ntload(mrow + cc), w[cc * 64 + d], acc);
        ntstore(out + (size_t)n * 256 + tid, acc * 0.0625f);
    }
}

extern "C" void kernel_launch(void* const* d_in, const int* in_sizes, int n_in,
                              void* d_out, int out_size, void* d_ws, size_t ws_size,
                              hipStream_t stream) {
    (void)in_sizes; (void)n_in; (void)out_size; (void)ws_size;
    const float* node_feats = (const float*)d_in[0];
    const float* edge_attrs = (const float*)d_in[1];
    const float* edge_feats = (const float*)d_in[2];
    const float* lengths    = (const float*)d_in[3];
    const int*   edge_index = (const int*)d_in[4];
    const float* Wsc  = (const float*)d_in[5];
    const float* Wup0 = (const float*)d_in[6];
    const float* Wup1 = (const float*)d_in[7];
    const float* W1   = (const float*)d_in[8];
    const float* b1   = (const float*)d_in[9];
    const float* W2   = (const float*)d_in[10];
    const float* b2   = (const float*)d_in[11];
    const float* W3   = (const float*)d_in[12];
    const float* Ws   = (const float*)d_in[13];
    const float* Wv   = (const float*)d_in[14];

    char* ws = (char*)d_ws;
    u16*   ns_bf  = (u16*)(ws + OFF_NSBF);
    f32x4* sv     = (f32x4*)(ws + OFF_SV);
    float* m_g    = (float*)(ws + OFF_MG);
    u16*   twg    = (u16*)(ws + OFF_TW);
    u16*   W1f    = (u16*)(ws + OFF_W1F);
    u16*   W2f    = (u16*)(ws + OFF_W2F);
    u16*   W3f    = (u16*)(ws + OFF_W3F);
    int*   cnt    = (int*)(ws + OFF_CNT);
    int*   offs   = (int*)(ws + OFF_OFFS);
    int*   cursor = (int*)(ws + OFF_CUR);
    int*   esort  = (int*)(ws + OFF_ES);
    int*   ssort  = (int*)(ws + OFF_SS);
    int*   rsort  = (int*)(ws + OFF_RS);
    float* out    = (float*)d_out;

    hipMemsetAsync(cnt, 0, N_NODES * sizeof(int), stream);
    prep_w_kernel<<<15, 256, 0, stream>>>(W1, W2, W3, W1f, W2f, W3f);
    node_prep_kernel<<<N_NODES / 4, 256, 0, stream>>>(node_feats, Wsc, Wup0, Wup1, ns_bf, sv);
    hist_kernel<<<N_EDGES / 256, 256, 0, stream>>>(edge_index, cnt);
    scan_kernel<<<1, 1024, 0, stream>>>(cnt, offs, cursor);
    scatter_kernel<<<N_EDGES / 256, 256, 0, stream>>>(edge_index, cursor, esort, ssort, rsort);

    for (int ch = 0; ch < NCHUNK; ch++) {
        int n0 = ch * NPC;
        mlp_kernel<<<K3_BLOCKS, 256, 0, stream>>>(ns_bf, W1f, W2f, W3f, b1, b2,
                                                  edge_feats, lengths,
                                                  esort, ssort, rsort, offs, twg, n0);
        seg_kernel<<<NPC / 4, 256, 0, stream>>>(sv, edge_attrs, esort, ssort,
                                                offs, twg, m_g, n0);
    }
    out_kernel<<<(N_NODES + 39) / 40, 256, 0, stream>>>(m_g, Ws, Wv, out);
}

// Round 5
// 384.457 us; speedup vs baseline: 2.0832x; 1.6565x over previous
//
#include <hip/hip_runtime.h>

#define N_NODES 20000
#define N_EDGES 320000
#define INV_SQRT3 0.5773502691896258f
#define NCHUNK 4
#define NPC 5000            // nodes per chunk
#define EDGE_CAP 84032      // max edges per chunk (mean 80000, sigma ~245)
#define K3_BLOCKS (EDGE_CAP / 64)

typedef unsigned short u16;
typedef unsigned int u32;
typedef __attribute__((ext_vector_type(8))) short short8;
typedef __attribute__((ext_vector_type(4))) float f32x4;
typedef __attribute__((ext_vector_type(4))) u32 u32x4v;

// ---- workspace layout (bytes) ----
static const size_t OFF_NSBF = 0;            // N*64 bf16
static const size_t OFF_SV   = 2560000;      // N*64 float4 (s, v0, v1, v2)
static const size_t OFF_MG   = 23040000;     // N*512 f32
static const size_t OFF_TW   = 64000000;     // EDGE_CAP*256 fp16
static const size_t OFF_W1F  = 107024384;
static const size_t OFF_W2F  = 107044864;
static const size_t OFF_W3F  = 107053056;
static const size_t OFF_CNT  = 107085824;
static const size_t OFF_OFFS = 107165824;
static const size_t OFF_CUR  = 107245888;
static const size_t OFF_ES   = 107325888;
static const size_t OFF_SS   = 108605888;
static const size_t OFF_RS   = 109885888;    // ends ~111.2MB

static __device__ __forceinline__ u16 f2bf(float x) {
    union { float f; u32 u; } c; c.f = x;
    u32 u = c.u + 0x7fffu + ((c.u >> 16) & 1u);
    return (u16)(u >> 16);
}
static __device__ __forceinline__ u16 f2h(float x) {
    union { _Float16 h; u16 u; } c; c.h = (_Float16)x; return c.u;
}
static __device__ __forceinline__ float h2f(u32 b) {
    union { u16 u; _Float16 h; } c; c.u = (u16)b; return (float)c.h;
}
static __device__ __forceinline__ f32x4 mfma16(short8 a, short8 b, f32x4 c) {
    return __builtin_amdgcn_mfma_f32_16x16x32_bf16(a, b, c, 0, 0, 0);
}
static __device__ __forceinline__ float silu(float x) {
    return x / (1.0f + __expf(-x));
}
template <typename T>
static __device__ __forceinline__ T ntload(const T* p) { return __builtin_nontemporal_load(p); }
template <typename T>
static __device__ __forceinline__ void ntstore(T* p, T v) { __builtin_nontemporal_store(v, p); }

// ---- prep: weights -> MFMA B-fragment order (bf16) ----
__global__ void prep_w_kernel(const float* __restrict__ W1, const float* __restrict__ W2,
                              const float* __restrict__ W3,
                              u16* __restrict__ W1f, u16* __restrict__ W2f, u16* __restrict__ W3f) {
    int t = blockIdx.x * 256 + threadIdx.x;
    if (t >= 3840) return;
    int l = t & 63, grp = t >> 6;
    int hi = l >> 4, lo = l & 15;
    if (grp < 20) {
        int kk = grp >> 2, jt = grp & 3;
#pragma unroll
        for (int e2 = 0; e2 < 8; e2++) {
            int k = kk * 32 + hi * 8 + e2, j = jt * 16 + lo;
            W1f[(size_t)(grp * 64 + l) * 8 + e2] = (k < 137) ? f2bf(W1[k * 64 + j]) : (u16)0;
        }
    } else if (grp < 28) {
        int g = grp - 20; int kk = g >> 2, jt = g & 3;
#pragma unroll
        for (int e2 = 0; e2 < 8; e2++) {
            int k = kk * 32 + hi * 8 + e2, j = jt * 16 + lo;
            W2f[(size_t)(g * 64 + l) * 8 + e2] = f2bf(W2[k * 64 + j]);
        }
    } else {
        int g = grp - 28; int kk = g >> 4, jt = g & 15;
#pragma unroll
        for (int e2 = 0; e2 < 8; e2++) {
            int k = kk * 32 + hi * 8 + e2, j = jt * 16 + lo;
            W3f[(size_t)(g * 64 + l) * 8 + e2] = f2bf(W3[k * 256 + j]);
        }
    }
}

// ---- node precompute: ns = s@Wsc (bf16), sv[n][c] = {s_up, v_up0, v_up1, v_up2} ----
__global__ void node_prep_kernel(const float* __restrict__ node_feats,
                                 const float* __restrict__ Wsc, const float* __restrict__ Wup0,
                                 const float* __restrict__ Wup1,
                                 u16* __restrict__ ns_bf, f32x4* __restrict__ sv) {
    __shared__ float nf[4][256];
    int tid = threadIdx.x;
    int wv = tid >> 6, l = tid & 63;
    int n = blockIdx.x * 4 + wv;
    *(float4*)&nf[wv][l * 4] = *(const float4*)(node_feats + (size_t)n * 256 + l * 4);
    __syncthreads();
    float a_ns = 0.f, a_su = 0.f, av0 = 0.f, av1 = 0.f, av2 = 0.f;
    for (int c = 0; c < 64; c++) {
        float sc = nf[wv][c];
        a_ns = fmaf(sc, Wsc[c * 64 + l], a_ns);
        a_su = fmaf(sc, Wup0[c * 64 + l], a_su);
        float wu = Wup1[c * 64 + l];
        av0 = fmaf(nf[wv][64 + c * 3 + 0], wu, av0);
        av1 = fmaf(nf[wv][64 + c * 3 + 1], wu, av1);
        av2 = fmaf(nf[wv][64 + c * 3 + 2], wu, av2);
    }
    ns_bf[(size_t)n * 64 + l] = f2bf(a_ns);
    f32x4 o; o.x = a_su; o.y = av0; o.z = av1; o.w = av2;
    sv[(size_t)n * 64 + l] = o;
}

// ---- counting sort by rcv ----
__global__ void hist_kernel(const int* __restrict__ ei, int* __restrict__ cnt) {
    int e = blockIdx.x * 256 + threadIdx.x;
    if (e < N_EDGES) atomicAdd(&cnt[ei[N_EDGES + e]], 1);
}

__global__ void scan_kernel(const int* __restrict__ cnt, int* __restrict__ offs,
                            int* __restrict__ cursor) {
    __shared__ int buf[1024];
    int t = threadIdx.x;
    int base = t * 20;
    int loc[20];
    int tot = 0;
#pragma unroll
    for (int i = 0; i < 20; i++) {
        int idx = base + i;
        int v = (idx < N_NODES) ? cnt[idx] : 0;
        loc[i] = tot;
        tot += v;
    }
    buf[t] = tot;
    __syncthreads();
    for (int d = 1; d < 1024; d <<= 1) {
        int add = (t >= d) ? buf[t - d] : 0;
        __syncthreads();
        buf[t] += add;
        __syncthreads();
    }
    int ebase = buf[t] - tot;
#pragma unroll
    for (int i = 0; i < 20; i++) {
        int idx = base + i;
        if (idx < N_NODES) { int o = ebase + loc[i]; offs[idx] = o; cursor[idx] = o; }
    }
    if (t == 1023) offs[N_NODES] = buf[1023];
}

__global__ void scatter_kernel(const int* __restrict__ ei, int* __restrict__ cursor,
                               int* __restrict__ esort, int* __restrict__ ssort,
                               int* __restrict__ rsort) {
    int e = blockIdx.x * 256 + threadIdx.x;
    if (e < N_EDGES) {
        int sn = ei[e];
        int rc = ei[N_EDGES + e];
        int pos = atomicAdd(&cursor[rc], 1);
        esort[pos] = e;
        ssort[pos] = sn;
        rsort[pos] = rc;
    }
}

// ---- K3: edge MLP over sorted edges, bf16 MFMA, tw -> fp16 (NT) ----
__global__ __launch_bounds__(256, 4) void mlp_kernel(
    const u16* __restrict__ ns_bf,
    const u16* __restrict__ W1f, const u16* __restrict__ W2f, const u16* __restrict__ W3f,
    const float* __restrict__ b1, const float* __restrict__ b2,
    const float* __restrict__ edge_feats, const float* __restrict__ lengths,
    const int* __restrict__ esort, const int* __restrict__ ssort, const int* __restrict__ rsort,
    const int* __restrict__ offs, u16* __restrict__ twg, int n0) {

    __shared__ u16 mlp[64][168];
    __shared__ u16 h1s[64][72];
    __shared__ u16 h2s[64][72];

    const int tid = threadIdx.x;
    const int l = tid & 63;
    const int lo16 = l & 15;
    const int hi = l >> 4;
    const int w = tid >> 6;
    const int erow = (w << 4) | lo16;
    const int koff = hi * 8;
    const int drow = (w << 4) + hi * 4;

    const int cb = offs[n0];
    const int ce = offs[n0 + NPC];
    const int p0 = cb + blockIdx.x * 64;
    if (p0 >= ce) return;
    int tcnt = ce - p0; if (tcnt > 64) tcnt = 64;

    const short8* w1frag = (const short8*)W1f;
    const short8* w2frag = (const short8*)W2f;
    const short8* w3frag = (const short8*)W3f;

    float bb1[4], bb2[4];
#pragma unroll
    for (int jt = 0; jt < 4; jt++) { bb1[jt] = b1[jt * 16 + lo16]; bb2[jt] = b2[jt * 16 + lo16]; }

    // zero pad region k=136..167 (K rows 137..159 of W1f are zero, but NaN*0=NaN)
    {
        int rr = tid >> 2, pp = tid & 3;
        uint4 z = {0, 0, 0, 0};
        *(uint4*)&mlp[rr][136 + pp * 8] = z;
    }

    // stage gathered edge inputs
    {
        int es = tid >> 2, part = tid & 3;
        if (es < tcnt) {
            int e = esort[p0 + es];
            int sn = ssort[p0 + es];
            int rc = rsort[p0 + es];
            const uint4* ps = (const uint4*)(ns_bf + (size_t)sn * 64 + part * 16);
            uint4 s0 = ps[0], s1 = ps[1];
            *(uint4*)&mlp[es][part * 16] = s0;
            *(uint4*)&mlp[es][part * 16 + 8] = s1;
            const uint4* pr = (const uint4*)(ns_bf + (size_t)rc * 64 + part * 16);
            uint4 r0v = pr[0], r1v = pr[1];
            *(uint4*)&mlp[es][64 + part * 16] = r0v;
            *(uint4*)&mlp[es][64 + part * 16 + 8] = r1v;
            if (part == 0) {
                float4 f0 = *(const float4*)(edge_feats + (size_t)e * 8);
                float4 f1 = *(const float4*)(edge_feats + (size_t)e * 8 + 4);
                u32 pk0 = (u32)f2bf(f0.x) | ((u32)f2bf(f0.y) << 16);
                u32 pk1 = (u32)f2bf(f0.z) | ((u32)f2bf(f0.w) << 16);
                u32 pk2 = (u32)f2bf(f1.x) | ((u32)f2bf(f1.y) << 16);
                u32 pk3 = (u32)f2bf(f1.z) | ((u32)f2bf(f1.w) << 16);
                uint4 pk = {pk0, pk1, pk2, pk3};
                *(uint4*)&mlp[es][128] = pk;
                mlp[es][136] = f2bf(lengths[e]);
            }
        }
    }
    __syncthreads();

    // layer 1: (64x160) @ (160x64)
    f32x4 a1c[4];
#pragma unroll
    for (int jt = 0; jt < 4; jt++) a1c[jt] = (f32x4)(0.0f);
#pragma unroll
    for (int kk = 0; kk < 5; kk++) {
        short8 af = *(const short8*)&mlp[erow][kk * 32 + koff];
        const short8* wb = w1frag + kk * 256 + l;
        a1c[0] = mfma16(af, wb[0],   a1c[0]);
        a1c[1] = mfma16(af, wb[64],  a1c[1]);
        a1c[2] = mfma16(af, wb[128], a1c[2]);
        a1c[3] = mfma16(af, wb[192], a1c[3]);
    }
#pragma unroll
    for (int jt = 0; jt < 4; jt++) {
#pragma unroll
        for (int r = 0; r < 4; r++) {
            float x = a1c[jt][r] + bb1[jt];
            h1s[drow + r][jt * 16 + lo16] = f2bf(silu(x));
        }
    }
    __syncthreads();

    // layer 2: (64x64) @ (64x64)
    f32x4 a2c[4];
#pragma unroll
    for (int jt = 0; jt < 4; jt++) a2c[jt] = (f32x4)(0.0f);
#pragma unroll
    for (int kk = 0; kk < 2; kk++) {
        short8 af = *(const short8*)&h1s[erow][kk * 32 + koff];
        const short8* wb = w2frag + kk * 256 + l;
        a2c[0] = mfma16(af, wb[0],   a2c[0]);
        a2c[1] = mfma16(af, wb[64],  a2c[1]);
        a2c[2] = mfma16(af, wb[128], a2c[2]);
        a2c[3] = mfma16(af, wb[192], a2c[3]);
    }
#pragma unroll
    for (int jt = 0; jt < 4; jt++) {
#pragma unroll
        for (int r = 0; r < 4; r++) {
            float x = a2c[jt][r] + bb2[jt];
            h2s[drow + r][jt * 16 + lo16] = f2bf(silu(x));
        }
    }
    __syncthreads();

    // layer 3: (64x64) @ (64x256)
    f32x4 tw[16];
#pragma unroll
    for (int jt = 0; jt < 16; jt++) tw[jt] = (f32x4)(0.0f);
#pragma unroll
    for (int kk = 0; kk < 2; kk++) {
        short8 af = *(const short8*)&h2s[erow][kk * 32 + koff];
        const short8* wb = w3frag + kk * 1024 + l;
#pragma unroll
        for (int jt = 0; jt < 16; jt++) tw[jt] = mfma16(af, wb[jt * 64], tw[jt]);
    }

    // store tw as fp16: layout per edge: [lo16][k=q*4+j3]  (16 fp16 = 32B per lo16)
    int relrow = blockIdx.x * 64 + drow;
#pragma unroll
    for (int r = 0; r < 4; r++) {
        if (drow + r < tcnt) {
            u32 q0a = (u32)f2h(tw[0][r])  | ((u32)f2h(tw[1][r])  << 16);
            u32 q0b = (u32)f2h(tw[2][r])  | ((u32)f2h(tw[3][r])  << 16);
            u32 q1a = (u32)f2h(tw[4][r])  | ((u32)f2h(tw[5][r])  << 16);
            u32 q1b = (u32)f2h(tw[6][r])  | ((u32)f2h(tw[7][r])  << 16);
            u32 q2a = (u32)f2h(tw[8][r])  | ((u32)f2h(tw[9][r])  << 16);
            u32 q2b = (u32)f2h(tw[10][r]) | ((u32)f2h(tw[11][r]) << 16);
            u32 q3a = (u32)f2h(tw[12][r]) | ((u32)f2h(tw[13][r]) << 16);
            u32 q3b = (u32)f2h(tw[14][r]) | ((u32)f2h(tw[15][r]) << 16);
            u16* dst = twg + (size_t)(relrow + r) * 256 + lo16 * 16;
            u32x4v A = {q0a, q0b, q1a, q1b};
            u32x4v B = {q2a, q2b, q3a, q3b};
            ntstore((u32x4v*)dst, A);
            ntstore(((u32x4v*)dst) + 1, B);
        }
    }
}

// ---- K4: one wave per node; tensor products + register segment-sum ----
__global__ __launch_bounds__(256, 4) void seg_kernel(
    const f32x4* __restrict__ sv, const float* __restrict__ edge_attrs,
    const int* __restrict__ esort, const int* __restrict__ ssort,
    const int* __restrict__ offs, const u16* __restrict__ twg,
    float* __restrict__ m_g, int n0) {
    const int lane = threadIdx.x & 63;
    const int wv = threadIdx.x >> 6;
    const int n = n0 + blockIdx.x * 4 + wv;
    const int c = lane;
    const int jt = c >> 4, lo16 = c & 15;
    const int cb = offs[n0];
    const int e0 = offs[n], e1 = offs[n + 1];
    float a_m0 = 0.f, a_m0b = 0.f;
    float a20 = 0.f, a21 = 0.f, a22 = 0.f, a30 = 0.f, a31 = 0.f, a32 = 0.f;
#pragma unroll 2
    for (int pos = e0; pos < e1; ++pos) {
        int e = esort[pos];
        int sn = ssort[pos];
        const u16* twp = twg + (size_t)(pos - cb) * 256 + lo16 * 16;
        u32x4v ta = ntload((const u32x4v*)twp);
        u32x4v tb = ntload(((const u32x4v*)twp) + 1);
        f32x4 y4 = *(const f32x4*)(edge_attrs + (size_t)e * 4);
        f32x4 s4 = sv[(size_t)sn * 64 + c];
        u32 wwa = (jt & 2) ? ta.y : ta.x;
        u32 wwb = (jt & 2) ? ta.w : ta.z;
        u32 wwc = (jt & 2) ? tb.y : tb.x;
        u32 wwd = (jt & 2) ? tb.w : tb.z;
        int sh = (jt & 1) << 4;
        float w0 = h2f((wwa >> sh) & 0xffffu);
        float w1 = h2f((wwb >> sh) & 0xffffu);
        float w2 = h2f((wwc >> sh) & 0xffffu);
        float w3 = h2f((wwd >> sh) & 0xffffu);
        float xs = s4.x, xv0 = s4.y, xv1 = s4.z, xv2 = s4.w;
        float y0 = y4.x, ya = y4.y, yb = y4.z, yc = y4.w;
        a_m0 = fmaf(xs * y0, w0, a_m0);
        float dv = xv0 * ya + xv1 * yb + xv2 * yc;
        a_m0b = fmaf(dv, w1, a_m0b);
        float sw2 = xs * w2;
        a20 = fmaf(sw2, ya, a20); a21 = fmaf(sw2, yb, a21); a22 = fmaf(sw2, yc, a22);
        float yw3 = y0 * w3;
        a30 = fmaf(xv0, yw3, a30); a31 = fmaf(xv1, yw3, a31); a32 = fmaf(xv2, yw3, a32);
    }
    float* mr = m_g + (size_t)n * 512;
    ntstore(mr + c,        a_m0);
    ntstore(mr + 64 + c,   a_m0b * INV_SQRT3);
    ntstore(mr + 128 + c,  a20);
    ntstore(mr + 192 + c,  a30);
    ntstore(mr + 256 + c,  a21);
    ntstore(mr + 320 + c,  a31);
    ntstore(mr + 384 + c,  a22);
    ntstore(mr + 448 + c,  a32);
}

// ---- K5: per-node output transform; wave-per-node, LDS-staged {Ws,Wv} float2,
//      double-buffered m-row staging with block barriers, NT m_g reads ----
__global__ __launch_bounds__(256, 2) void out_kernel(
    const float* __restrict__ m_g, const float* __restrict__ Ws, const float* __restrict__ Wv,
    float* __restrict__ out) {
    __shared__ float2 WL[8192];          // [c*64+d] = {Ws[c,d], Wv[c,d]}  64 KB
    __shared__ float MB[2][4][512];      // double-buffered per-wave m rows, 16 KB

    const int tid = threadIdx.x;
    for (int i = tid; i < 8192; i += 256) {
        float2 w2v; w2v.x = Ws[i]; w2v.y = Wv[i];
        WL[i] = w2v;
    }

    const int lane = tid & 63;
    const int wv = tid >> 6;
    const int nb = blockIdx.x * 40;

    // preload batch 0 (node nb+wv) into registers
    size_t base0 = (size_t)(nb + wv) * 512 + lane * 4;
    f32x4 ca = ntload((const f32x4*)(m_g + base0));
    f32x4 cb = ntload((const f32x4*)(m_g + base0 + 256));

    for (int it = 0; it < 10; ++it) {
        const int cur = it & 1;
        // stage current batch into LDS
        *(f32x4*)&MB[cur][wv][lane * 4] = ca;
        *(f32x4*)&MB[cur][wv][256 + lane * 4] = cb;
        // prefetch next batch (register), clamped to a valid node
        int nn = nb + (it + 1) * 4 + wv;
        if (nn >= N_NODES) nn = nb + wv;
        size_t bn = (size_t)nn * 512 + lane * 4;
        ca = ntload((const f32x4*)(m_g + bn));
        cb = ntload((const f32x4*)(m_g + bn + 256));

        __syncthreads();   // LDS writes (WL on it==0, MB[cur]) visible before reads

        const float* mb = MB[cur][wv];
        float as = 0.f, av0 = 0.f, av1 = 0.f, av2 = 0.f;
#pragma unroll
        for (int cg = 0; cg < 128; cg += 4) {
            f32x4 m0q = *(const f32x4*)&mb[cg];
            f32x4 v0q = *(const f32x4*)&mb[128 + cg];
            f32x4 v1q = *(const f32x4*)&mb[256 + cg];
            f32x4 v2q = *(const f32x4*)&mb[384 + cg];
#pragma unroll
            for (int j = 0; j < 4; j++) {
                float2 wv2 = WL[(cg + j) * 64 + lane];
                as  = fmaf(m0q[j], wv2.x, as);
                av0 = fmaf(v0q[j], wv2.y, av0);
                av1 = fmaf(v1q[j], wv2.y, av1);
                av2 = fmaf(v2q[j], wv2.y, av2);
            }
        }
        int n = nb + it * 4 + wv;
        f32x4 o;
        o.x = as * 0.0625f; o.y = av0 * 0.0625f; o.z = av1 * 0.0625f; o.w = av2 * 0.0625f;
        ntstore((f32x4*)(out + (size_t)n * 256 + lane * 4), o);
        __syncthreads();   // all reads of MB[cur] done before it's overwritten next+1 iter
    }
}

extern "C" void kernel_launch(void* const* d_in, const int* in_sizes, int n_in,
                              void* d_out, int out_size, void* d_ws, size_t ws_size,
                              hipStream_t stream) {
    (void)in_sizes; (void)n_in; (void)out_size; (void)ws_size;
    const float* node_feats = (const float*)d_in[0];
    const float* edge_attrs = (const float*)d_in[1];
    const float* edge_feats = (const float*)d_in[2];
    const float* lengths    = (const float*)d_in[3];
    const int*   edge_index = (const int*)d_in[4];
    const float* Wsc  = (const float*)d_in[5];
    const float* Wup0 = (const float*)d_in[6];
    const float* Wup1 = (const float*)d_in[7];
    const float* W1   = (const float*)d_in[8];
    const float* b1   = (const float*)d_in[9];
    const float* W2   = (const float*)d_in[10];
    const float* b2   = (const float*)d_in[11];
    const float* W3   = (const float*)d_in[12];
    const float* Ws   = (const float*)d_in[13];
    const float* Wv   = (const float*)d_in[14];

    char* ws = (char*)d_ws;
    u16*   ns_bf  = (u16*)(ws + OFF_NSBF);
    f32x4* sv     = (f32x4*)(ws + OFF_SV);
    float* m_g    = (float*)(ws + OFF_MG);
    u16*   twg    = (u16*)(ws + OFF_TW);
    u16*   W1f    = (u16*)(ws + OFF_W1F);
    u16*   W2f    = (u16*)(ws + OFF_W2F);
    u16*   W3f    = (u16*)(ws + OFF_W3F);
    int*   cnt    = (int*)(ws + OFF_CNT);
    int*   offs   = (int*)(ws + OFF_OFFS);
    int*   cursor = (int*)(ws + OFF_CUR);
    int*   esort  = (int*)(ws + OFF_ES);
    int*   ssort  = (int*)(ws + OFF_SS);
    int*   rsort  = (int*)(ws + OFF_RS);
    float* out    = (float*)d_out;

    (void)hipMemsetAsync(cnt, 0, N_NODES * sizeof(int), stream);
    prep_w_kernel<<<15, 256, 0, stream>>>(W1, W2, W3, W1f, W2f, W3f);
    node_prep_kernel<<<N_NODES / 4, 256, 0, stream>>>(node_feats, Wsc, Wup0, Wup1, ns_bf, sv);
    hist_kernel<<<N_EDGES / 256, 256, 0, stream>>>(edge_index, cnt);
    scan_kernel<<<1, 1024, 0, stream>>>(cnt, offs, cursor);
    scatter_kernel<<<N_EDGES / 256, 256, 0, stream>>>(edge_index, cursor, esort, ssort, rsort);

    for (int ch = 0; ch < NCHUNK; ch++) {
        int n0 = ch * NPC;
        mlp_kernel<<<K3_BLOCKS, 256, 0, stream>>>(ns_bf, W1f, W2f, W3f, b1, b2,
                                                  edge_feats, lengths,
                                                  esort, ssort, rsort, offs, twg, n0);
        seg_kernel<<<NPC / 4, 256, 0, stream>>>(sv, edge_attrs, esort, ssort,
                                                offs, twg, m_g, n0);
    }
    out_kernel<<<N_NODES / 40, 256, 0, stream>>>(m_g, Ws, Wv, out);
}

// Round 6
// 338.287 us; speedup vs baseline: 2.3675x; 1.1365x over previous
//
#include <hip/hip_runtime.h>

#define N_NODES 20000
#define N_EDGES 320000
#define INV_SQRT3 0.5773502691896258f
#define NCHUNK 4
#define NPC 5000            // nodes per chunk
#define EDGE_CAP 84032      // max edges per chunk (mean 80000, sigma ~245)
#define K3_BLOCKS (EDGE_CAP / 64)

typedef unsigned short u16;
typedef unsigned int u32;
typedef __attribute__((ext_vector_type(8))) short short8;
typedef __attribute__((ext_vector_type(4))) float f32x4;
typedef __attribute__((ext_vector_type(4))) u32 u32x4v;

// ---- workspace layout (bytes) ----
static const size_t OFF_NSBF = 0;            // N*64 bf16
static const size_t OFF_SV   = 2560000;      // N*64 float4 (s, v0, v1, v2)
static const size_t OFF_MG   = 23040000;     // N*512 f32
static const size_t OFF_TW   = 64000000;     // EDGE_CAP*256 fp16
static const size_t OFF_W1F  = 107024384;
static const size_t OFF_W2F  = 107044864;
static const size_t OFF_W3F  = 107053056;
static const size_t OFF_CNT  = 107085824;
static const size_t OFF_OFFS = 107165824;
static const size_t OFF_CUR  = 107245888;    // cursor (sort); reused as WSF after scatter
static const size_t OFF_ES   = 107325888;
static const size_t OFF_SS   = 108605888;
static const size_t OFF_RS   = 109885888;    // ends ~111.2MB
// WSF layout (in OFF_CUR region, 64KB of 80KB): Ws_hi[8192], Ws_lo[8192], Wv_hi[8192], Wv_lo[8192] u16

static __device__ __forceinline__ u16 f2bf(float x) {
    union { float f; u32 u; } c; c.f = x;
    u32 u = c.u + 0x7fffu + ((c.u >> 16) & 1u);
    return (u16)(u >> 16);
}
static __device__ __forceinline__ float bf2f(u16 b) {
    union { u32 u; float f; } c; c.u = (u32)b << 16; return c.f;
}
static __device__ __forceinline__ u16 f2h(float x) {
    union { _Float16 h; u16 u; } c; c.h = (_Float16)x; return c.u;
}
static __device__ __forceinline__ float h2f(u32 b) {
    union { u16 u; _Float16 h; } c; c.u = (u16)b; return (float)c.h;
}
static __device__ __forceinline__ f32x4 mfma16(short8 a, short8 b, f32x4 c) {
    return __builtin_amdgcn_mfma_f32_16x16x32_bf16(a, b, c, 0, 0, 0);
}
static __device__ __forceinline__ float silu(float x) {
    return x / (1.0f + __expf(-x));
}
template <typename T>
static __device__ __forceinline__ T ntload(const T* p) { return __builtin_nontemporal_load(p); }
template <typename T>
static __device__ __forceinline__ void ntstore(T* p, T v) { __builtin_nontemporal_store(v, p); }

// ---- prep: weights -> MFMA B-fragment order (bf16) ----
__global__ void prep_w_kernel(const float* __restrict__ W1, const float* __restrict__ W2,
                              const float* __restrict__ W3,
                              u16* __restrict__ W1f, u16* __restrict__ W2f, u16* __restrict__ W3f) {
    int t = blockIdx.x * 256 + threadIdx.x;
    if (t >= 3840) return;
    int l = t & 63, grp = t >> 6;
    int hi = l >> 4, lo = l & 15;
    if (grp < 20) {
        int kk = grp >> 2, jt = grp & 3;
#pragma unroll
        for (int e2 = 0; e2 < 8; e2++) {
            int k = kk * 32 + hi * 8 + e2, j = jt * 16 + lo;
            W1f[(size_t)(grp * 64 + l) * 8 + e2] = (k < 137) ? f2bf(W1[k * 64 + j]) : (u16)0;
        }
    } else if (grp < 28) {
        int g = grp - 20; int kk = g >> 2, jt = g & 3;
#pragma unroll
        for (int e2 = 0; e2 < 8; e2++) {
            int k = kk * 32 + hi * 8 + e2, j = jt * 16 + lo;
            W2f[(size_t)(g * 64 + l) * 8 + e2] = f2bf(W2[k * 64 + j]);
        }
    } else {
        int g = grp - 28; int kk = g >> 4, jt = g & 15;
#pragma unroll
        for (int e2 = 0; e2 < 8; e2++) {
            int k = kk * 32 + hi * 8 + e2, j = jt * 16 + lo;
            W3f[(size_t)(g * 64 + l) * 8 + e2] = f2bf(W3[k * 256 + j]);
        }
    }
}

// ---- prep2: Ws/Wv -> MFMA B-fragments with hi/lo bf16 split (runs after scatter, into cursor region) ----
__global__ void prep_w2_kernel(const float* __restrict__ Ws, const float* __restrict__ Wv,
                               u16* __restrict__ WSF) {
    int t = blockIdx.x * 256 + threadIdx.x;
    if (t >= 2048) return;
    int l = t & 63, grp = t >> 6;          // grp 0..31
    int wsel = grp >> 4;                    // 0 = Ws, 1 = Wv
    int g = grp & 15;
    int kk = g >> 2, jt = g & 3;
    int hi = l >> 4, lo = l & 15;
    const float* W = wsel ? Wv : Ws;
    u16* dh = WSF + (size_t)wsel * 16384;
    u16* dl = dh + 8192;
    size_t base = (size_t)(g * 64 + l) * 8;
#pragma unroll
    for (int e2 = 0; e2 < 8; e2++) {
        int k = kk * 32 + hi * 8 + e2, d = jt * 16 + lo;
        float w = W[k * 64 + d];
        u16 h = f2bf(w);
        float r = w - bf2f(h);
        dh[base + e2] = h;
        dl[base + e2] = f2bf(r);
    }
}

// ---- node precompute: ns = s@Wsc (bf16), sv[n][c] = {s_up, v_up0, v_up1, v_up2} ----
__global__ void node_prep_kernel(const float* __restrict__ node_feats,
                                 const float* __restrict__ Wsc, const float* __restrict__ Wup0,
                                 const float* __restrict__ Wup1,
                                 u16* __restrict__ ns_bf, f32x4* __restrict__ sv) {
    __shared__ float nf[4][256];
    int tid = threadIdx.x;
    int wv = tid >> 6, l = tid & 63;
    int n = blockIdx.x * 4 + wv;
    *(float4*)&nf[wv][l * 4] = *(const float4*)(node_feats + (size_t)n * 256 + l * 4);
    __syncthreads();
    float a_ns = 0.f, a_su = 0.f, av0 = 0.f, av1 = 0.f, av2 = 0.f;
    for (int c = 0; c < 64; c++) {
        float sc = nf[wv][c];
        a_ns = fmaf(sc, Wsc[c * 64 + l], a_ns);
        a_su = fmaf(sc, Wup0[c * 64 + l], a_su);
        float wu = Wup1[c * 64 + l];
        av0 = fmaf(nf[wv][64 + c * 3 + 0], wu, av0);
        av1 = fmaf(nf[wv][64 + c * 3 + 1], wu, av1);
        av2 = fmaf(nf[wv][64 + c * 3 + 2], wu, av2);
    }
    ns_bf[(size_t)n * 64 + l] = f2bf(a_ns);
    f32x4 o; o.x = a_su; o.y = av0; o.z = av1; o.w = av2;
    sv[(size_t)n * 64 + l] = o;
}

// ---- counting sort by rcv ----
__global__ void hist_kernel(const int* __restrict__ ei, int* __restrict__ cnt) {
    int e = blockIdx.x * 256 + threadIdx.x;
    if (e < N_EDGES) atomicAdd(&cnt[ei[N_EDGES + e]], 1);
}

__global__ void scan_kernel(const int* __restrict__ cnt, int* __restrict__ offs,
                            int* __restrict__ cursor) {
    __shared__ int buf[1024];
    int t = threadIdx.x;
    int base = t * 20;
    int loc[20];
    int tot = 0;
#pragma unroll
    for (int i = 0; i < 20; i++) {
        int idx = base + i;
        int v = (idx < N_NODES) ? cnt[idx] : 0;
        loc[i] = tot;
        tot += v;
    }
    buf[t] = tot;
    __syncthreads();
    for (int d = 1; d < 1024; d <<= 1) {
        int add = (t >= d) ? buf[t - d] : 0;
        __syncthreads();
        buf[t] += add;
        __syncthreads();
    }
    int ebase = buf[t] - tot;
#pragma unroll
    for (int i = 0; i < 20; i++) {
        int idx = base + i;
        if (idx < N_NODES) { int o = ebase + loc[i]; offs[idx] = o; cursor[idx] = o; }
    }
    if (t == 1023) offs[N_NODES] = buf[1023];
}

__global__ void scatter_kernel(const int* __restrict__ ei, int* __restrict__ cursor,
                               int* __restrict__ esort, int* __restrict__ ssort,
                               int* __restrict__ rsort) {
    int e = blockIdx.x * 256 + threadIdx.x;
    if (e < N_EDGES) {
        int sn = ei[e];
        int rc = ei[N_EDGES + e];
        int pos = atomicAdd(&cursor[rc], 1);
        esort[pos] = e;
        ssort[pos] = sn;
        rsort[pos] = rc;
    }
}

// ---- K3: edge MLP over sorted edges, bf16 MFMA, tw -> fp16 (NT) ----
__global__ __launch_bounds__(256, 4) void mlp_kernel(
    const u16* __restrict__ ns_bf,
    const u16* __restrict__ W1f, const u16* __restrict__ W2f, const u16* __restrict__ W3f,
    const float* __restrict__ b1, const float* __restrict__ b2,
    const float* __restrict__ edge_feats, const float* __restrict__ lengths,
    const int* __restrict__ esort, const int* __restrict__ ssort, const int* __restrict__ rsort,
    const int* __restrict__ offs, u16* __restrict__ twg, int n0) {

    __shared__ u16 mlp[64][168];
    __shared__ u16 h1s[64][72];
    __shared__ u16 h2s[64][72];

    const int tid = threadIdx.x;
    const int l = tid & 63;
    const int lo16 = l & 15;
    const int hi = l >> 4;
    const int w = tid >> 6;
    const int erow = (w << 4) | lo16;
    const int koff = hi * 8;
    const int drow = (w << 4) + hi * 4;

    const int cb = offs[n0];
    const int ce = offs[n0 + NPC];
    const int p0 = cb + blockIdx.x * 64;
    if (p0 >= ce) return;
    int tcnt = ce - p0; if (tcnt > 64) tcnt = 64;

    const short8* w1frag = (const short8*)W1f;
    const short8* w2frag = (const short8*)W2f;
    const short8* w3frag = (const short8*)W3f;

    float bb1[4], bb2[4];
#pragma unroll
    for (int jt = 0; jt < 4; jt++) { bb1[jt] = b1[jt * 16 + lo16]; bb2[jt] = b2[jt * 16 + lo16]; }

    // zero pad region k=136..167 (K rows 137..159 of W1f are zero, but NaN*0=NaN)
    {
        int rr = tid >> 2, pp = tid & 3;
        uint4 z = {0, 0, 0, 0};
        *(uint4*)&mlp[rr][136 + pp * 8] = z;
    }

    // stage gathered edge inputs
    {
        int es = tid >> 2, part = tid & 3;
        if (es < tcnt) {
            int e = esort[p0 + es];
            int sn = ssort[p0 + es];
            int rc = rsort[p0 + es];
            const uint4* ps = (const uint4*)(ns_bf + (size_t)sn * 64 + part * 16);
            uint4 s0 = ps[0], s1 = ps[1];
            *(uint4*)&mlp[es][part * 16] = s0;
            *(uint4*)&mlp[es][part * 16 + 8] = s1;
            const uint4* pr = (const uint4*)(ns_bf + (size_t)rc * 64 + part * 16);
            uint4 r0v = pr[0], r1v = pr[1];
            *(uint4*)&mlp[es][64 + part * 16] = r0v;
            *(uint4*)&mlp[es][64 + part * 16 + 8] = r1v;
            if (part == 0) {
                float4 f0 = *(const float4*)(edge_feats + (size_t)e * 8);
                float4 f1 = *(const float4*)(edge_feats + (size_t)e * 8 + 4);
                u32 pk0 = (u32)f2bf(f0.x) | ((u32)f2bf(f0.y) << 16);
                u32 pk1 = (u32)f2bf(f0.z) | ((u32)f2bf(f0.w) << 16);
                u32 pk2 = (u32)f2bf(f1.x) | ((u32)f2bf(f1.y) << 16);
                u32 pk3 = (u32)f2bf(f1.z) | ((u32)f2bf(f1.w) << 16);
                uint4 pk = {pk0, pk1, pk2, pk3};
                *(uint4*)&mlp[es][128] = pk;
                mlp[es][136] = f2bf(lengths[e]);
            }
        }
    }
    __syncthreads();

    // layer 1: (64x160) @ (160x64)
    f32x4 a1c[4];
#pragma unroll
    for (int jt = 0; jt < 4; jt++) a1c[jt] = (f32x4)(0.0f);
#pragma unroll
    for (int kk = 0; kk < 5; kk++) {
        short8 af = *(const short8*)&mlp[erow][kk * 32 + koff];
        const short8* wb = w1frag + kk * 256 + l;
        a1c[0] = mfma16(af, wb[0],   a1c[0]);
        a1c[1] = mfma16(af, wb[64],  a1c[1]);
        a1c[2] = mfma16(af, wb[128], a1c[2]);
        a1c[3] = mfma16(af, wb[192], a1c[3]);
    }
#pragma unroll
    for (int jt = 0; jt < 4; jt++) {
#pragma unroll
        for (int r = 0; r < 4; r++) {
            float x = a1c[jt][r] + bb1[jt];
            h1s[drow + r][jt * 16 + lo16] = f2bf(silu(x));
        }
    }
    __syncthreads();

    // layer 2: (64x64) @ (64x64)
    f32x4 a2c[4];
#pragma unroll
    for (int jt = 0; jt < 4; jt++) a2c[jt] = (f32x4)(0.0f);
#pragma unroll
    for (int kk = 0; kk < 2; kk++) {
        short8 af = *(const short8*)&h1s[erow][kk * 32 + koff];
        const short8* wb = w2frag + kk * 256 + l;
        a2c[0] = mfma16(af, wb[0],   a2c[0]);
        a2c[1] = mfma16(af, wb[64],  a2c[1]);
        a2c[2] = mfma16(af, wb[128], a2c[2]);
        a2c[3] = mfma16(af, wb[192], a2c[3]);
    }
#pragma unroll
    for (int jt = 0; jt < 4; jt++) {
#pragma unroll
        for (int r = 0; r < 4; r++) {
            float x = a2c[jt][r] + bb2[jt];
            h2s[drow + r][jt * 16 + lo16] = f2bf(silu(x));
        }
    }
    __syncthreads();

    // layer 3: (64x64) @ (64x256)
    f32x4 tw[16];
#pragma unroll
    for (int jt = 0; jt < 16; jt++) tw[jt] = (f32x4)(0.0f);
#pragma unroll
    for (int kk = 0; kk < 2; kk++) {
        short8 af = *(const short8*)&h2s[erow][kk * 32 + koff];
        const short8* wb = w3frag + kk * 1024 + l;
#pragma unroll
        for (int jt = 0; jt < 16; jt++) tw[jt] = mfma16(af, wb[jt * 64], tw[jt]);
    }

    // store tw as fp16: layout per edge: [lo16][k=q*4+j3]  (16 fp16 = 32B per lo16)
    int relrow = blockIdx.x * 64 + drow;
#pragma unroll
    for (int r = 0; r < 4; r++) {
        if (drow + r < tcnt) {
            u32 q0a = (u32)f2h(tw[0][r])  | ((u32)f2h(tw[1][r])  << 16);
            u32 q0b = (u32)f2h(tw[2][r])  | ((u32)f2h(tw[3][r])  << 16);
            u32 q1a = (u32)f2h(tw[4][r])  | ((u32)f2h(tw[5][r])  << 16);
            u32 q1b = (u32)f2h(tw[6][r])  | ((u32)f2h(tw[7][r])  << 16);
            u32 q2a = (u32)f2h(tw[8][r])  | ((u32)f2h(tw[9][r])  << 16);
            u32 q2b = (u32)f2h(tw[10][r]) | ((u32)f2h(tw[11][r]) << 16);
            u32 q3a = (u32)f2h(tw[12][r]) | ((u32)f2h(tw[13][r]) << 16);
            u32 q3b = (u32)f2h(tw[14][r]) | ((u32)f2h(tw[15][r]) << 16);
            u16* dst = twg + (size_t)(relrow + r) * 256 + lo16 * 16;
            u32x4v A = {q0a, q0b, q1a, q1b};
            u32x4v B = {q2a, q2b, q3a, q3b};
            ntstore((u32x4v*)dst, A);
            ntstore(((u32x4v*)dst) + 1, B);
        }
    }
}

// ---- K4: one wave per node; tensor products + register segment-sum ----
__global__ __launch_bounds__(256, 4) void seg_kernel(
    const f32x4* __restrict__ sv, const float* __restrict__ edge_attrs,
    const int* __restrict__ esort, const int* __restrict__ ssort,
    const int* __restrict__ offs, const u16* __restrict__ twg,
    float* __restrict__ m_g, int n0) {
    const int lane = threadIdx.x & 63;
    const int wv = threadIdx.x >> 6;
    const int n = n0 + blockIdx.x * 4 + wv;
    const int c = lane;
    const int jt = c >> 4, lo16 = c & 15;
    const int cb = offs[n0];
    const int e0 = offs[n], e1 = offs[n + 1];
    float a_m0 = 0.f, a_m0b = 0.f;
    float a20 = 0.f, a21 = 0.f, a22 = 0.f, a30 = 0.f, a31 = 0.f, a32 = 0.f;
#pragma unroll 2
    for (int pos = e0; pos < e1; ++pos) {
        int e = esort[pos];
        int sn = ssort[pos];
        const u16* twp = twg + (size_t)(pos - cb) * 256 + lo16 * 16;
        u32x4v ta = ntload((const u32x4v*)twp);
        u32x4v tb = ntload(((const u32x4v*)twp) + 1);
        f32x4 y4 = *(const f32x4*)(edge_attrs + (size_t)e * 4);
        f32x4 s4 = sv[(size_t)sn * 64 + c];
        u32 wwa = (jt & 2) ? ta.y : ta.x;
        u32 wwb = (jt & 2) ? ta.w : ta.z;
        u32 wwc = (jt & 2) ? tb.y : tb.x;
        u32 wwd = (jt & 2) ? tb.w : tb.z;
        int sh = (jt & 1) << 4;
        float w0 = h2f((wwa >> sh) & 0xffffu);
        float w1 = h2f((wwb >> sh) & 0xffffu);
        float w2 = h2f((wwc >> sh) & 0xffffu);
        float w3 = h2f((wwd >> sh) & 0xffffu);
        float xs = s4.x, xv0 = s4.y, xv1 = s4.z, xv2 = s4.w;
        float y0 = y4.x, ya = y4.y, yb = y4.z, yc = y4.w;
        a_m0 = fmaf(xs * y0, w0, a_m0);
        float dv = xv0 * ya + xv1 * yb + xv2 * yc;
        a_m0b = fmaf(dv, w1, a_m0b);
        float sw2 = xs * w2;
        a20 = fmaf(sw2, ya, a20); a21 = fmaf(sw2, yb, a21); a22 = fmaf(sw2, yc, a22);
        float yw3 = y0 * w3;
        a30 = fmaf(xv0, yw3, a30); a31 = fmaf(xv1, yw3, a31); a32 = fmaf(xv2, yw3, a32);
    }
    float* mr = m_g + (size_t)n * 512;
    ntstore(mr + c,        a_m0);
    ntstore(mr + 64 + c,   a_m0b * INV_SQRT3);
    ntstore(mr + 128 + c,  a20);
    ntstore(mr + 192 + c,  a30);
    ntstore(mr + 256 + c,  a21);
    ntstore(mr + 320 + c,  a31);
    ntstore(mr + 384 + c,  a22);
    ntstore(mr + 448 + c,  a32);
}

// ---- K5: MFMA epilogue. 64 nodes/block, 4 waves, no LDS, no barriers.
//      out_s = m0@Ws/16, out_v[i] = m1[i]@Wv/16; A hi/lo bf16 split (fp32-accurate) ----
__global__ __launch_bounds__(256, 2) void out_kernel(
    const float* __restrict__ m_g, const u16* __restrict__ WSF,
    float* __restrict__ out) {
    const int tid = threadIdx.x;
    const int lane = tid & 63;
    const int w = tid >> 6;
    const int lo16 = lane & 15;
    const int hi = lane >> 4;
    const int nb = blockIdx.x * 64 + w * 16;

    int arow_n = nb + lo16;
    if (arow_n > N_NODES - 1) arow_n = N_NODES - 1;
    const float* arow = m_g + (size_t)arow_n * 512 + hi * 8;

    const short8* bsh = (const short8*)WSF;              // Ws hi
    const short8* bsl = (const short8*)(WSF + 8192);     // Ws lo
    const short8* bvh = (const short8*)(WSF + 16384);    // Wv hi
    const short8* bvl = (const short8*)(WSF + 24576);    // Wv lo

    f32x4 acc[4][4];
#pragma unroll
    for (int q = 0; q < 4; q++)
#pragma unroll
        for (int jt = 0; jt < 4; jt++) acc[q][jt] = (f32x4)(0.0f);

#pragma unroll
    for (int kk = 0; kk < 4; kk++) {
        short8 ahi[4], alo[4];
#pragma unroll
        for (int q = 0; q < 4; q++) {
            const float* p = arow + q * 128 + kk * 32;
            f32x4 x0 = ntload((const f32x4*)p);
            f32x4 x1 = ntload((const f32x4*)(p + 4));
#pragma unroll
            for (int j = 0; j < 4; j++) {
                u16 h0 = f2bf(x0[j]);
                ahi[q][j] = (short)h0;
                alo[q][j] = (short)f2bf(x0[j] - bf2f(h0));
                u16 h1 = f2bf(x1[j]);
                ahi[q][4 + j] = (short)h1;
                alo[q][4 + j] = (short)f2bf(x1[j] - bf2f(h1));
            }
        }
#pragma unroll
        for (int jt = 0; jt < 4; jt++) {
            int bidx = (kk * 4 + jt) * 64 + lane;
            short8 wh_s = bsh[bidx];
            short8 wl_s = bsl[bidx];
            short8 wh_v = bvh[bidx];
            short8 wl_v = bvl[bidx];
            acc[0][jt] = mfma16(ahi[0], wh_s, acc[0][jt]);
            acc[0][jt] = mfma16(alo[0], wh_s, acc[0][jt]);
            acc[0][jt] = mfma16(ahi[0], wl_s, acc[0][jt]);
#pragma unroll
            for (int q = 1; q < 4; q++) {
                acc[q][jt] = mfma16(ahi[q], wh_v, acc[q][jt]);
                acc[q][jt] = mfma16(alo[q], wh_v, acc[q][jt]);
                acc[q][jt] = mfma16(ahi[q], wl_v, acc[q][jt]);
            }
        }
    }

    // write: D row = hi*4+r, col = jt*16+lo16; out[n][d] = {s,v0,v1,v2}/16
#pragma unroll
    for (int r = 0; r < 4; r++) {
        int n = nb + hi * 4 + r;
        if (n < N_NODES) {
#pragma unroll
            for (int jt = 0; jt < 4; jt++) {
                int d = jt * 16 + lo16;
                f32x4 o;
                o.x = acc[0][jt][r] * 0.0625f;
                o.y = acc[1][jt][r] * 0.0625f;
                o.z = acc[2][jt][r] * 0.0625f;
                o.w = acc[3][jt][r] * 0.0625f;
                ntstore((f32x4*)(out + (size_t)n * 256 + d * 4), o);
            }
        }
    }
}

extern "C" void kernel_launch(void* const* d_in, const int* in_sizes, int n_in,
                              void* d_out, int out_size, void* d_ws, size_t ws_size,
                              hipStream_t stream) {
    (void)in_sizes; (void)n_in; (void)out_size; (void)ws_size;
    const float* node_feats = (const float*)d_in[0];
    const float* edge_attrs = (const float*)d_in[1];
    const float* edge_feats = (const float*)d_in[2];
    const float* lengths    = (const float*)d_in[3];
    const int*   edge_index = (const int*)d_in[4];
    const float* Wsc  = (const float*)d_in[5];
    const float* Wup0 = (const float*)d_in[6];
    const float* Wup1 = (const float*)d_in[7];
    const float* W1   = (const float*)d_in[8];
    const float* b1   = (const float*)d_in[9];
    const float* W2   = (const float*)d_in[10];
    const float* b2   = (const float*)d_in[11];
    const float* W3   = (const float*)d_in[12];
    const float* Ws   = (const float*)d_in[13];
    const float* Wv   = (const float*)d_in[14];

    char* ws = (char*)d_ws;
    u16*   ns_bf  = (u16*)(ws + OFF_NSBF);
    f32x4* sv     = (f32x4*)(ws + OFF_SV);
    float* m_g    = (float*)(ws + OFF_MG);
    u16*   twg    = (u16*)(ws + OFF_TW);
    u16*   W1f    = (u16*)(ws + OFF_W1F);
    u16*   W2f    = (u16*)(ws + OFF_W2F);
    u16*   W3f    = (u16*)(ws + OFF_W3F);
    int*   cnt    = (int*)(ws + OFF_CNT);
    int*   offs   = (int*)(ws + OFF_OFFS);
    int*   cursor = (int*)(ws + OFF_CUR);
    u16*   WSF    = (u16*)(ws + OFF_CUR);   // reuses cursor region after scatter
    int*   esort  = (int*)(ws + OFF_ES);
    int*   ssort  = (int*)(ws + OFF_SS);
    int*   rsort  = (int*)(ws + OFF_RS);
    float* out    = (float*)d_out;

    (void)hipMemsetAsync(cnt, 0, N_NODES * sizeof(int), stream);
    prep_w_kernel<<<15, 256, 0, stream>>>(W1, W2, W3, W1f, W2f, W3f);
    node_prep_kernel<<<N_NODES / 4, 256, 0, stream>>>(node_feats, Wsc, Wup0, Wup1, ns_bf, sv);
    hist_kernel<<<N_EDGES / 256, 256, 0, stream>>>(edge_index, cnt);
    scan_kernel<<<1, 1024, 0, stream>>>(cnt, offs, cursor);
    scatter_kernel<<<N_EDGES / 256, 256, 0, stream>>>(edge_index, cursor, esort, ssort, rsort);
    prep_w2_kernel<<<8, 256, 0, stream>>>(Ws, Wv, WSF);   // after scatter: cursor region is free

    for (int ch = 0; ch < NCHUNK; ch++) {
        int n0 = ch * NPC;
        mlp_kernel<<<K3_BLOCKS, 256, 0, stream>>>(ns_bf, W1f, W2f, W3f, b1, b2,
                                                  edge_feats, lengths,
                                                  esort, ssort, rsort, offs, twg, n0);
        seg_kernel<<<NPC / 4, 256, 0, stream>>>(sv, edge_attrs, esort, ssort,
                                                offs, twg, m_g, n0);
    }
    out_kernel<<<(N_NODES + 63) / 64, 256, 0, stream>>>(m_g, WSF, out);
}

// Round 7
// 333.541 us; speedup vs baseline: 2.4012x; 1.0142x over previous
//
#include <hip/hip_runtime.h>

#define N_NODES 20000
#define N_EDGES 320000
#define INV_SQRT3 0.5773502691896258f
#define NCHUNK 4
#define NPC 5000            // nodes per chunk
#define EDGE_CAP 84032      // max edges per chunk (mean 80000, sigma ~245)
#define K3_BLOCKS (EDGE_CAP / 64)

typedef unsigned short u16;
typedef unsigned int u32;
typedef __attribute__((ext_vector_type(8))) short short8;
typedef __attribute__((ext_vector_type(4))) float f32x4;
typedef __attribute__((ext_vector_type(4))) u32 u32x4v;

// ---- workspace layout (bytes) ----
static const size_t OFF_NSBF = 0;            // N*64 bf16
static const size_t OFF_SV   = 2560000;      // N*64 float4 (s, v0, v1, v2)
static const size_t OFF_MG   = 23040000;     // N*512 f32
static const size_t OFF_TW   = 64000000;     // EDGE_CAP*256 fp16
static const size_t OFF_W1F  = 107024384;
static const size_t OFF_W2F  = 107044864;
static const size_t OFF_W3F  = 107053056;
static const size_t OFF_CNT  = 107085824;
static const size_t OFF_OFFS = 107165824;
static const size_t OFF_CUR  = 107245888;    // cursor (sort); reused as WSF after scatter
static const size_t OFF_ES   = 107325888;
static const size_t OFF_SS   = 108605888;
static const size_t OFF_RS   = 109885888;    // ends ~111.2MB
// WSF layout (in OFF_CUR region, 64KB of 80KB): Ws_hi[8192], Ws_lo[8192], Wv_hi[8192], Wv_lo[8192] u16

static __device__ __forceinline__ u16 f2bf(float x) {
    union { float f; u32 u; } c; c.f = x;
    u32 u = c.u + 0x7fffu + ((c.u >> 16) & 1u);
    return (u16)(u >> 16);
}
static __device__ __forceinline__ float bf2f(u16 b) {
    union { u32 u; float f; } c; c.u = (u32)b << 16; return c.f;
}
static __device__ __forceinline__ u16 f2h(float x) {
    union { _Float16 h; u16 u; } c; c.h = (_Float16)x; return c.u;
}
static __device__ __forceinline__ float h2f(u32 b) {
    union { u16 u; _Float16 h; } c; c.u = (u16)b; return (float)c.h;
}
static __device__ __forceinline__ f32x4 mfma16(short8 a, short8 b, f32x4 c) {
    return __builtin_amdgcn_mfma_f32_16x16x32_bf16(a, b, c, 0, 0, 0);
}
static __device__ __forceinline__ float silu(float x) {
    return x / (1.0f + __expf(-x));
}
template <typename T>
static __device__ __forceinline__ T ntload(const T* p) { return __builtin_nontemporal_load(p); }
template <typename T>
static __device__ __forceinline__ void ntstore(T* p, T v) { __builtin_nontemporal_store(v, p); }

// ---- prep: weights -> MFMA B-fragment order (bf16) ----
__global__ void prep_w_kernel(const float* __restrict__ W1, const float* __restrict__ W2,
                              const float* __restrict__ W3,
                              u16* __restrict__ W1f, u16* __restrict__ W2f, u16* __restrict__ W3f) {
    int t = blockIdx.x * 256 + threadIdx.x;
    if (t >= 3840) return;
    int l = t & 63, grp = t >> 6;
    int hi = l >> 4, lo = l & 15;
    if (grp < 20) {
        int kk = grp >> 2, jt = grp & 3;
#pragma unroll
        for (int e2 = 0; e2 < 8; e2++) {
            int k = kk * 32 + hi * 8 + e2, j = jt * 16 + lo;
            W1f[(size_t)(grp * 64 + l) * 8 + e2] = (k < 137) ? f2bf(W1[k * 64 + j]) : (u16)0;
        }
    } else if (grp < 28) {
        int g = grp - 20; int kk = g >> 2, jt = g & 3;
#pragma unroll
        for (int e2 = 0; e2 < 8; e2++) {
            int k = kk * 32 + hi * 8 + e2, j = jt * 16 + lo;
            W2f[(size_t)(g * 64 + l) * 8 + e2] = f2bf(W2[k * 64 + j]);
        }
    } else {
        int g = grp - 28; int kk = g >> 4, jt = g & 15;
#pragma unroll
        for (int e2 = 0; e2 < 8; e2++) {
            int k = kk * 32 + hi * 8 + e2, j = jt * 16 + lo;
            W3f[(size_t)(g * 64 + l) * 8 + e2] = f2bf(W3[k * 256 + j]);
        }
    }
}

// ---- prep2: Ws/Wv -> MFMA B-fragments with hi/lo bf16 split ----
__global__ void prep_w2_kernel(const float* __restrict__ Ws, const float* __restrict__ Wv,
                               u16* __restrict__ WSF) {
    int t = blockIdx.x * 256 + threadIdx.x;
    if (t >= 2048) return;
    int l = t & 63, grp = t >> 6;          // grp 0..31
    int wsel = grp >> 4;                    // 0 = Ws, 1 = Wv
    int g = grp & 15;
    int kk = g >> 2, jt = g & 3;
    int hi = l >> 4, lo = l & 15;
    const float* W = wsel ? Wv : Ws;
    u16* dh = WSF + (size_t)wsel * 16384;
    u16* dl = dh + 8192;
    size_t base = (size_t)(g * 64 + l) * 8;
#pragma unroll
    for (int e2 = 0; e2 < 8; e2++) {
        int k = kk * 32 + hi * 8 + e2, d = jt * 16 + lo;
        float w = W[k * 64 + d];
        u16 h = f2bf(w);
        float r = w - bf2f(h);
        dh[base + e2] = h;
        dl[base + e2] = f2bf(r);
    }
}

// ---- node precompute v2: 32 nodes/block, 8 nodes/thread, LDS-staged node rows ----
// ns = s@Wsc (bf16), sv[n][c] = {s_up, v_up0, v_up1, v_up2}
__global__ __launch_bounds__(256) void node_prep_kernel(
    const float* __restrict__ node_feats,
    const float* __restrict__ Wsc, const float* __restrict__ Wup0,
    const float* __restrict__ Wup1,
    u16* __restrict__ ns_bf, f32x4* __restrict__ sv) {
    __shared__ float nf[32][256];      // 32 KB
    const int tid = threadIdx.x;
    const int nb = blockIdx.x * 32;

    // stage 32 node rows, coalesced
    {
        const float4* src = (const float4*)(node_feats + (size_t)nb * 256);
        float4* dst = (float4*)nf;
        for (int i = tid; i < 2048; i += 256) dst[i] = src[i];
    }
    __syncthreads();

    const int wv = tid >> 6;            // wave 0..3 -> nodes wv*8 .. wv*8+7
    const int l = tid & 63;             // output column d
    const int j0 = wv * 8;

    float a_ns[8], a_su[8], av0[8], av1[8], av2[8];
#pragma unroll
    for (int j = 0; j < 8; j++) { a_ns[j] = 0.f; a_su[j] = 0.f; av0[j] = 0.f; av1[j] = 0.f; av2[j] = 0.f; }

    for (int c = 0; c < 64; c++) {
        float wsc = Wsc[c * 64 + l];
        float wu0 = Wup0[c * 64 + l];
        float wu1 = Wup1[c * 64 + l];
#pragma unroll
        for (int j = 0; j < 8; j++) {
            const float* row = nf[j0 + j];
            float s = row[c];
            float v0 = row[64 + c * 3 + 0];
            float v1 = row[64 + c * 3 + 1];
            float v2 = row[64 + c * 3 + 2];
            a_ns[j] = fmaf(s, wsc, a_ns[j]);
            a_su[j] = fmaf(s, wu0, a_su[j]);
            av0[j] = fmaf(v0, wu1, av0[j]);
            av1[j] = fmaf(v1, wu1, av1[j]);
            av2[j] = fmaf(v2, wu1, av2[j]);
        }
    }
#pragma unroll
    for (int j = 0; j < 8; j++) {
        int n = nb + j0 + j;
        ns_bf[(size_t)n * 64 + l] = f2bf(a_ns[j]);
        f32x4 o; o.x = a_su[j]; o.y = av0[j]; o.z = av1[j]; o.w = av2[j];
        sv[(size_t)n * 64 + l] = o;
    }
}

// ---- counting sort by rcv ----
__global__ void hist_kernel(const int* __restrict__ ei, int* __restrict__ cnt) {
    int e = blockIdx.x * 256 + threadIdx.x;
    if (e < N_EDGES) atomicAdd(&cnt[ei[N_EDGES + e]], 1);
}

__global__ void scan_kernel(const int* __restrict__ cnt, int* __restrict__ offs,
                            int* __restrict__ cursor) {
    __shared__ int buf[1024];
    int t = threadIdx.x;
    int base = t * 20;
    int loc[20];
    int tot = 0;
#pragma unroll
    for (int i = 0; i < 20; i++) {
        int idx = base + i;
        int v = (idx < N_NODES) ? cnt[idx] : 0;
        loc[i] = tot;
        tot += v;
    }
    buf[t] = tot;
    __syncthreads();
    for (int d = 1; d < 1024; d <<= 1) {
        int add = (t >= d) ? buf[t - d] : 0;
        __syncthreads();
        buf[t] += add;
        __syncthreads();
    }
    int ebase = buf[t] - tot;
#pragma unroll
    for (int i = 0; i < 20; i++) {
        int idx = base + i;
        if (idx < N_NODES) { int o = ebase + loc[i]; offs[idx] = o; cursor[idx] = o; }
    }
    if (t == 1023) offs[N_NODES] = buf[1023];
}

__global__ void scatter_kernel(const int* __restrict__ ei, int* __restrict__ cursor,
                               int* __restrict__ esort, int* __restrict__ ssort,
                               int* __restrict__ rsort) {
    int e = blockIdx.x * 256 + threadIdx.x;
    if (e < N_EDGES) {
        int sn = ei[e];
        int rc = ei[N_EDGES + e];
        int pos = atomicAdd(&cursor[rc], 1);
        esort[pos] = e;
        ssort[pos] = sn;
        rsort[pos] = rc;
    }
}

// ---- K3: edge MLP over sorted edges, bf16 MFMA, tw -> fp16 (cached: L3 feeds seg) ----
__global__ __launch_bounds__(256, 4) void mlp_kernel(
    const u16* __restrict__ ns_bf,
    const u16* __restrict__ W1f, const u16* __restrict__ W2f, const u16* __restrict__ W3f,
    const float* __restrict__ b1, const float* __restrict__ b2,
    const float* __restrict__ edge_feats, const float* __restrict__ lengths,
    const int* __restrict__ esort, const int* __restrict__ ssort, const int* __restrict__ rsort,
    const int* __restrict__ offs, u16* __restrict__ twg, int n0) {

    __shared__ u16 mlp[64][168];
    __shared__ u16 h1s[64][72];
    __shared__ u16 h2s[64][72];

    const int tid = threadIdx.x;
    const int l = tid & 63;
    const int lo16 = l & 15;
    const int hi = l >> 4;
    const int w = tid >> 6;
    const int erow = (w << 4) | lo16;
    const int koff = hi * 8;
    const int drow = (w << 4) + hi * 4;

    const int cb = offs[n0];
    const int ce = offs[n0 + NPC];
    const int p0 = cb + blockIdx.x * 64;
    if (p0 >= ce) return;
    int tcnt = ce - p0; if (tcnt > 64) tcnt = 64;

    const short8* w1frag = (const short8*)W1f;
    const short8* w2frag = (const short8*)W2f;
    const short8* w3frag = (const short8*)W3f;

    float bb1[4], bb2[4];
#pragma unroll
    for (int jt = 0; jt < 4; jt++) { bb1[jt] = b1[jt * 16 + lo16]; bb2[jt] = b2[jt * 16 + lo16]; }

    // zero pad region k=136..167 (K rows 137..159 of W1f are zero, but NaN*0=NaN)
    {
        int rr = tid >> 2, pp = tid & 3;
        uint4 z = {0, 0, 0, 0};
        *(uint4*)&mlp[rr][136 + pp * 8] = z;
    }

    // stage gathered edge inputs
    {
        int es = tid >> 2, part = tid & 3;
        if (es < tcnt) {
            int e = esort[p0 + es];
            int sn = ssort[p0 + es];
            int rc = rsort[p0 + es];
            const uint4* ps = (const uint4*)(ns_bf + (size_t)sn * 64 + part * 16);
            uint4 s0 = ps[0], s1 = ps[1];
            *(uint4*)&mlp[es][part * 16] = s0;
            *(uint4*)&mlp[es][part * 16 + 8] = s1;
            const uint4* pr = (const uint4*)(ns_bf + (size_t)rc * 64 + part * 16);
            uint4 r0v = pr[0], r1v = pr[1];
            *(uint4*)&mlp[es][64 + part * 16] = r0v;
            *(uint4*)&mlp[es][64 + part * 16 + 8] = r1v;
            if (part == 0) {
                float4 f0 = *(const float4*)(edge_feats + (size_t)e * 8);
                float4 f1 = *(const float4*)(edge_feats + (size_t)e * 8 + 4);
                u32 pk0 = (u32)f2bf(f0.x) | ((u32)f2bf(f0.y) << 16);
                u32 pk1 = (u32)f2bf(f0.z) | ((u32)f2bf(f0.w) << 16);
                u32 pk2 = (u32)f2bf(f1.x) | ((u32)f2bf(f1.y) << 16);
                u32 pk3 = (u32)f2bf(f1.z) | ((u32)f2bf(f1.w) << 16);
                uint4 pk = {pk0, pk1, pk2, pk3};
                *(uint4*)&mlp[es][128] = pk;
                mlp[es][136] = f2bf(lengths[e]);
            }
        }
    }
    __syncthreads();

    // layer 1: (64x160) @ (160x64)
    f32x4 a1c[4];
#pragma unroll
    for (int jt = 0; jt < 4; jt++) a1c[jt] = (f32x4)(0.0f);
#pragma unroll
    for (int kk = 0; kk < 5; kk++) {
        short8 af = *(const short8*)&mlp[erow][kk * 32 + koff];
        const short8* wb = w1frag + kk * 256 + l;
        a1c[0] = mfma16(af, wb[0],   a1c[0]);
        a1c[1] = mfma16(af, wb[64],  a1c[1]);
        a1c[2] = mfma16(af, wb[128], a1c[2]);
        a1c[3] = mfma16(af, wb[192], a1c[3]);
    }
#pragma unroll
    for (int jt = 0; jt < 4; jt++) {
#pragma unroll
        for (int r = 0; r < 4; r++) {
            float x = a1c[jt][r] + bb1[jt];
            h1s[drow + r][jt * 16 + lo16] = f2bf(silu(x));
        }
    }
    __syncthreads();

    // layer 2: (64x64) @ (64x64)
    f32x4 a2c[4];
#pragma unroll
    for (int jt = 0; jt < 4; jt++) a2c[jt] = (f32x4)(0.0f);
#pragma unroll
    for (int kk = 0; kk < 2; kk++) {
        short8 af = *(const short8*)&h1s[erow][kk * 32 + koff];
        const short8* wb = w2frag + kk * 256 + l;
        a2c[0] = mfma16(af, wb[0],   a2c[0]);
        a2c[1] = mfma16(af, wb[64],  a2c[1]);
        a2c[2] = mfma16(af, wb[128], a2c[2]);
        a2c[3] = mfma16(af, wb[192], a2c[3]);
    }
#pragma unroll
    for (int jt = 0; jt < 4; jt++) {
#pragma unroll
        for (int r = 0; r < 4; r++) {
            float x = a2c[jt][r] + bb2[jt];
            h2s[drow + r][jt * 16 + lo16] = f2bf(silu(x));
        }
    }
    __syncthreads();

    // layer 3: (64x64) @ (64x256)
    f32x4 tw[16];
#pragma unroll
    for (int jt = 0; jt < 16; jt++) tw[jt] = (f32x4)(0.0f);
#pragma unroll
    for (int kk = 0; kk < 2; kk++) {
        short8 af = *(const short8*)&h2s[erow][kk * 32 + koff];
        const short8* wb = w3frag + kk * 1024 + l;
#pragma unroll
        for (int jt = 0; jt < 16; jt++) tw[jt] = mfma16(af, wb[jt * 64], tw[jt]);
    }

    // store tw as fp16 (regular stores -> L2/L3 resident for seg)
    int relrow = blockIdx.x * 64 + drow;
#pragma unroll
    for (int r = 0; r < 4; r++) {
        if (drow + r < tcnt) {
            u32 q0a = (u32)f2h(tw[0][r])  | ((u32)f2h(tw[1][r])  << 16);
            u32 q0b = (u32)f2h(tw[2][r])  | ((u32)f2h(tw[3][r])  << 16);
            u32 q1a = (u32)f2h(tw[4][r])  | ((u32)f2h(tw[5][r])  << 16);
            u32 q1b = (u32)f2h(tw[6][r])  | ((u32)f2h(tw[7][r])  << 16);
            u32 q2a = (u32)f2h(tw[8][r])  | ((u32)f2h(tw[9][r])  << 16);
            u32 q2b = (u32)f2h(tw[10][r]) | ((u32)f2h(tw[11][r]) << 16);
            u32 q3a = (u32)f2h(tw[12][r]) | ((u32)f2h(tw[13][r]) << 16);
            u32 q3b = (u32)f2h(tw[14][r]) | ((u32)f2h(tw[15][r]) << 16);
            u16* dst = twg + (size_t)(relrow + r) * 256 + lo16 * 16;
            u32x4v A = {q0a, q0b, q1a, q1b};
            u32x4v B = {q2a, q2b, q3a, q3b};
            *(u32x4v*)dst = A;
            *(((u32x4v*)dst) + 1) = B;
        }
    }
}

// ---- K4: one wave per node; tensor products + register segment-sum ----
__global__ __launch_bounds__(256, 4) void seg_kernel(
    const f32x4* __restrict__ sv, const float* __restrict__ edge_attrs,
    const int* __restrict__ esort, const int* __restrict__ ssort,
    const int* __restrict__ offs, const u16* __restrict__ twg,
    float* __restrict__ m_g, int n0) {
    const int lane = threadIdx.x & 63;
    const int wv = threadIdx.x >> 6;
    const int n = n0 + blockIdx.x * 4 + wv;
    const int c = lane;
    const int jt = c >> 4, lo16 = c & 15;
    const int cb = offs[n0];
    const int e0 = offs[n], e1 = offs[n + 1];
    float a_m0 = 0.f, a_m0b = 0.f;
    float a20 = 0.f, a21 = 0.f, a22 = 0.f, a30 = 0.f, a31 = 0.f, a32 = 0.f;
#pragma unroll 2
    for (int pos = e0; pos < e1; ++pos) {
        int e = esort[pos];
        int sn = ssort[pos];
        const u16* twp = twg + (size_t)(pos - cb) * 256 + lo16 * 16;
        u32x4v ta = *((const u32x4v*)twp);
        u32x4v tb = *(((const u32x4v*)twp) + 1);
        f32x4 y4 = *(const f32x4*)(edge_attrs + (size_t)e * 4);
        f32x4 s4 = sv[(size_t)sn * 64 + c];
        u32 wwa = (jt & 2) ? ta.y : ta.x;
        u32 wwb = (jt & 2) ? ta.w : ta.z;
        u32 wwc = (jt & 2) ? tb.y : tb.x;
        u32 wwd = (jt & 2) ? tb.w : tb.z;
        int sh = (jt & 1) << 4;
        float w0 = h2f((wwa >> sh) & 0xffffu);
        float w1 = h2f((wwb >> sh) & 0xffffu);
        float w2 = h2f((wwc >> sh) & 0xffffu);
        float w3 = h2f((wwd >> sh) & 0xffffu);
        float xs = s4.x, xv0 = s4.y, xv1 = s4.z, xv2 = s4.w;
        float y0 = y4.x, ya = y4.y, yb = y4.z, yc = y4.w;
        a_m0 = fmaf(xs * y0, w0, a_m0);
        float dv = xv0 * ya + xv1 * yb + xv2 * yc;
        a_m0b = fmaf(dv, w1, a_m0b);
        float sw2 = xs * w2;
        a20 = fmaf(sw2, ya, a20); a21 = fmaf(sw2, yb, a21); a22 = fmaf(sw2, yc, a22);
        float yw3 = y0 * w3;
        a30 = fmaf(xv0, yw3, a30); a31 = fmaf(xv1, yw3, a31); a32 = fmaf(xv2, yw3, a32);
    }
    float* mr = m_g + (size_t)n * 512;
    ntstore(mr + c,        a_m0);
    ntstore(mr + 64 + c,   a_m0b * INV_SQRT3);
    ntstore(mr + 128 + c,  a20);
    ntstore(mr + 192 + c,  a30);
    ntstore(mr + 256 + c,  a21);
    ntstore(mr + 320 + c,  a31);
    ntstore(mr + 384 + c,  a22);
    ntstore(mr + 448 + c,  a32);
}

// ---- K5: MFMA epilogue. 64 nodes/block, 4 waves, no LDS, no barriers. ----
__global__ __launch_bounds__(256, 2) void out_kernel(
    const float* __restrict__ m_g, const u16* __restrict__ WSF,
    float* __restrict__ out) {
    const int tid = threadIdx.x;
    const int lane = tid & 63;
    const int w = tid >> 6;
    const int lo16 = lane & 15;
    const int hi = lane >> 4;
    const int nb = blockIdx.x * 64 + w * 16;

    int arow_n = nb + lo16;
    if (arow_n > N_NODES - 1) arow_n = N_NODES - 1;
    const float* arow = m_g + (size_t)arow_n * 512 + hi * 8;

    const short8* bsh = (const short8*)WSF;              // Ws hi
    const short8* bsl = (const short8*)(WSF + 8192);     // Ws lo
    const short8* bvh = (const short8*)(WSF + 16384);    // Wv hi
    const short8* bvl = (const short8*)(WSF + 24576);    // Wv lo

    f32x4 acc[4][4];
#pragma unroll
    for (int q = 0; q < 4; q++)
#pragma unroll
        for (int jt = 0; jt < 4; jt++) acc[q][jt] = (f32x4)(0.0f);

#pragma unroll
    for (int kk = 0; kk < 4; kk++) {
        short8 ahi[4], alo[4];
#pragma unroll
        for (int q = 0; q < 4; q++) {
            const float* p = arow + q * 128 + kk * 32;
            f32x4 x0 = ntload((const f32x4*)p);
            f32x4 x1 = ntload((const f32x4*)(p + 4));
#pragma unroll
            for (int j = 0; j < 4; j++) {
                u16 h0 = f2bf(x0[j]);
                ahi[q][j] = (short)h0;
                alo[q][j] = (short)f2bf(x0[j] - bf2f(h0));
                u16 h1 = f2bf(x1[j]);
                ahi[q][4 + j] = (short)h1;
                alo[q][4 + j] = (short)f2bf(x1[j] - bf2f(h1));
            }
        }
#pragma unroll
        for (int jt = 0; jt < 4; jt++) {
            int bidx = (kk * 4 + jt) * 64 + lane;
            short8 wh_s = bsh[bidx];
            short8 wl_s = bsl[bidx];
            short8 wh_v = bvh[bidx];
            short8 wl_v = bvl[bidx];
            acc[0][jt] = mfma16(ahi[0], wh_s, acc[0][jt]);
            acc[0][jt] = mfma16(alo[0], wh_s, acc[0][jt]);
            acc[0][jt] = mfma16(ahi[0], wl_s, acc[0][jt]);
#pragma unroll
            for (int q = 1; q < 4; q++) {
                acc[q][jt] = mfma16(ahi[q], wh_v, acc[q][jt]);
                acc[q][jt] = mfma16(alo[q], wh_v, acc[q][jt]);
                acc[q][jt] = mfma16(ahi[q], wl_v, acc[q][jt]);
            }
        }
    }

    // write: D row = hi*4+r, col = jt*16+lo16; out[n][d] = {s,v0,v1,v2}/16
#pragma unroll
    for (int r = 0; r < 4; r++) {
        int n = nb + hi * 4 + r;
        if (n < N_NODES) {
#pragma unroll
            for (int jt = 0; jt < 4; jt++) {
                int d = jt * 16 + lo16;
                f32x4 o;
                o.x = acc[0][jt][r] * 0.0625f;
                o.y = acc[1][jt][r] * 0.0625f;
                o.z = acc[2][jt][r] * 0.0625f;
                o.w = acc[3][jt][r] * 0.0625f;
                ntstore((f32x4*)(out + (size_t)n * 256 + d * 4), o);
            }
        }
    }
}

extern "C" void kernel_launch(void* const* d_in, const int* in_sizes, int n_in,
                              void* d_out, int out_size, void* d_ws, size_t ws_size,
                              hipStream_t stream) {
    (void)in_sizes; (void)n_in; (void)out_size; (void)ws_size;
    const float* node_feats = (const float*)d_in[0];
    const float* edge_attrs = (const float*)d_in[1];
    const float* edge_feats = (const float*)d_in[2];
    const float* lengths    = (const float*)d_in[3];
    const int*   edge_index = (const int*)d_in[4];
    const float* Wsc  = (const float*)d_in[5];
    const float* Wup0 = (const float*)d_in[6];
    const float* Wup1 = (const float*)d_in[7];
    const float* W1   = (const float*)d_in[8];
    const float* b1   = (const float*)d_in[9];
    const float* W2   = (const float*)d_in[10];
    const float* b2   = (const float*)d_in[11];
    const float* W3   = (const float*)d_in[12];
    const float* Ws   = (const float*)d_in[13];
    const float* Wv   = (const float*)d_in[14];

    char* ws = (char*)d_ws;
    u16*   ns_bf  = (u16*)(ws + OFF_NSBF);
    f32x4* sv     = (f32x4*)(ws + OFF_SV);
    float* m_g    = (float*)(ws + OFF_MG);
    u16*   twg    = (u16*)(ws + OFF_TW);
    u16*   W1f    = (u16*)(ws + OFF_W1F);
    u16*   W2f    = (u16*)(ws + OFF_W2F);
    u16*   W3f    = (u16*)(ws + OFF_W3F);
    int*   cnt    = (int*)(ws + OFF_CNT);
    int*   offs   = (int*)(ws + OFF_OFFS);
    int*   cursor = (int*)(ws + OFF_CUR);
    u16*   WSF    = (u16*)(ws + OFF_CUR);   // reuses cursor region after scatter
    int*   esort  = (int*)(ws + OFF_ES);
    int*   ssort  = (int*)(ws + OFF_SS);
    int*   rsort  = (int*)(ws + OFF_RS);
    float* out    = (float*)d_out;

    (void)hipMemsetAsync(cnt, 0, N_NODES * sizeof(int), stream);
    prep_w_kernel<<<15, 256, 0, stream>>>(W1, W2, W3, W1f, W2f, W3f);
    node_prep_kernel<<<N_NODES / 32, 256, 0, stream>>>(node_feats, Wsc, Wup0, Wup1, ns_bf, sv);
    hist_kernel<<<N_EDGES / 256, 256, 0, stream>>>(edge_index, cnt);
    scan_kernel<<<1, 1024, 0, stream>>>(cnt, offs, cursor);
    scatter_kernel<<<N_EDGES / 256, 256, 0, stream>>>(edge_index, cursor, esort, ssort, rsort);
    prep_w2_kernel<<<8, 256, 0, stream>>>(Ws, Wv, WSF);   // after scatter: cursor region is free

    for (int ch = 0; ch < NCHUNK; ch++) {
        int n0 = ch * NPC;
        mlp_kernel<<<K3_BLOCKS, 256, 0, stream>>>(ns_bf, W1f, W2f, W3f, b1, b2,
                                                  edge_feats, lengths,
                                                  esort, ssort, rsort, offs, twg, n0);
        seg_kernel<<<NPC / 4, 256, 0, stream>>>(sv, edge_attrs, esort, ssort,
                                                offs, twg, m_g, n0);
    }
    out_kernel<<<(N_NODES + 63) / 64, 256, 0, stream>>>(m_g, WSF, out);
}

// Round 9
// 266.480 us; speedup vs baseline: 3.0055x; 1.2517x over previous
//
#include <hip/hip_runtime.h>

#define N_NODES 20000
#define N_EDGES 320000
#define INV_SQRT3 0.5773502691896258f

typedef unsigned short u16;
typedef unsigned int u32;
typedef __attribute__((ext_vector_type(8))) short short8;
typedef __attribute__((ext_vector_type(4))) float f32x4;
typedef __attribute__((ext_vector_type(4))) u32 u32x4v;

// ---- workspace layout (bytes), ws = 256 MiB ----
static const size_t OFF_NSBF = 0;            // N*64 bf16            (2,560,000)
static const size_t OFF_SV   = 2560000;      // N*64 float4          (20,480,000)
static const size_t OFF_MG   = 23040000;     // N*512 f32            (40,960,000)
static const size_t OFF_TW   = 64000000;     // E*256 fp16           (163,840,000)
static const size_t OFF_W1F  = 227840000;    // 20480
static const size_t OFF_W2F  = 227860480;    // 8192
static const size_t OFF_W3F  = 227868672;    // 32768
static const size_t OFF_WNF  = 227901440;    // 49152 (Wsc,Wup0,Wup1 hi/lo B-frags)
static const size_t OFF_CNT  = 227950592;    // 80000
static const size_t OFF_OFFS = 228030592;    // 80016 (80004 used, padded for align)
static const size_t OFF_CUR  = 228110608;    // 80000; reused as WSF (64KB) after scatter
static const size_t OFF_ES   = 228190608;    // 1,280,000
static const size_t OFF_SS   = 229470608;    // 1,280,000
static const size_t OFF_RS   = 230750608;    // 1,280,000 -> ends 232,030,608 < 268,435,456

static __device__ __forceinline__ u16 f2bf(float x) {
    union { float f; u32 u; } c; c.f = x;
    u32 u = c.u + 0x7fffu + ((c.u >> 16) & 1u);
    return (u16)(u >> 16);
}
static __device__ __forceinline__ float bf2f(u16 b) {
    union { u32 u; float f; } c; c.u = (u32)b << 16; return c.f;
}
static __device__ __forceinline__ u16 f2h(float x) {
    union { _Float16 h; u16 u; } c; c.h = (_Float16)x; return c.u;
}
static __device__ __forceinline__ float h2f(u32 b) {
    union { u16 u; _Float16 h; } c; c.u = (u16)b; return (float)c.h;
}
static __device__ __forceinline__ f32x4 mfma16(short8 a, short8 b, f32x4 c) {
    return __builtin_amdgcn_mfma_f32_16x16x32_bf16(a, b, c, 0, 0, 0);
}
static __device__ __forceinline__ float silu(float x) {
    return x / (1.0f + __expf(-x));
}
template <typename T>
static __device__ __forceinline__ T ntload(const T* p) { return __builtin_nontemporal_load(p); }
template <typename T>
static __device__ __forceinline__ void ntstore(T* p, T v) { __builtin_nontemporal_store(v, p); }

// ---- prep: MLP weights -> MFMA B-fragment order (bf16) ----
__global__ void prep_w_kernel(const float* __restrict__ W1, const float* __restrict__ W2,
                              const float* __restrict__ W3,
                              u16* __restrict__ W1f, u16* __restrict__ W2f, u16* __restrict__ W3f) {
    int t = blockIdx.x * 256 + threadIdx.x;
    if (t >= 3840) return;
    int l = t & 63, grp = t >> 6;
    int hi = l >> 4, lo = l & 15;
    if (grp < 20) {
        int kk = grp >> 2, jt = grp & 3;
#pragma unroll
        for (int e2 = 0; e2 < 8; e2++) {
            int k = kk * 32 + hi * 8 + e2, j = jt * 16 + lo;
            W1f[(size_t)(grp * 64 + l) * 8 + e2] = (k < 137) ? f2bf(W1[k * 64 + j]) : (u16)0;
        }
    } else if (grp < 28) {
        int g = grp - 20; int kk = g >> 2, jt = g & 3;
#pragma unroll
        for (int e2 = 0; e2 < 8; e2++) {
            int k = kk * 32 + hi * 8 + e2, j = jt * 16 + lo;
            W2f[(size_t)(g * 64 + l) * 8 + e2] = f2bf(W2[k * 64 + j]);
        }
    } else {
        int g = grp - 28; int kk = g >> 4, jt = g & 15;
#pragma unroll
        for (int e2 = 0; e2 < 8; e2++) {
            int k = kk * 32 + hi * 8 + e2, j = jt * 16 + lo;
            W3f[(size_t)(g * 64 + l) * 8 + e2] = f2bf(W3[k * 256 + j]);
        }
    }
}

// ---- prep: Wsc/Wup0/Wup1 -> hi/lo bf16 B-fragments (K=64, 8 g-groups each) ----
__global__ void prep_wn_kernel(const float* __restrict__ Wsc, const float* __restrict__ Wup0,
                               const float* __restrict__ Wup1, u16* __restrict__ WNF) {
    int t = blockIdx.x * 256 + threadIdx.x;
    if (t >= 1536) return;
    int mat = t >> 9;                 // 0..2
    int rem = t & 511;
    int g = rem >> 6, l = rem & 63;
    int kk = g >> 2, jt = g & 3, hi = l >> 4, lo = l & 15;
    const float* W = (mat == 0) ? Wsc : (mat == 1) ? Wup0 : Wup1;
    u16* dh = WNF + (size_t)mat * 8192 + (size_t)(g * 64 + l) * 8;
    u16* dl = dh + 4096;
#pragma unroll
    for (int e2 = 0; e2 < 8; e2++) {
        int k = kk * 32 + hi * 8 + e2, d = jt * 16 + lo;
        float w = W[k * 64 + d];
        u16 h = f2bf(w);
        dh[e2] = h;
        dl[e2] = f2bf(w - bf2f(h));
    }
}

// ---- prep2: Ws/Wv -> MFMA B-fragments with hi/lo bf16 split (K=128, 16 g-groups) ----
__global__ void prep_w2_kernel(const float* __restrict__ Ws, const float* __restrict__ Wv,
                               u16* __restrict__ WSF) {
    int t = blockIdx.x * 256 + threadIdx.x;
    if (t >= 2048) return;
    int l = t & 63, grp = t >> 6;          // grp 0..31
    int wsel = grp >> 4;                    // 0 = Ws, 1 = Wv
    int g = grp & 15;
    int kk = g >> 2, jt = g & 3;
    int hi = l >> 4, lo = l & 15;
    const float* W = wsel ? Wv : Ws;
    u16* dh = WSF + (size_t)wsel * 16384;
    u16* dl = dh + 8192;
    size_t base = (size_t)(g * 64 + l) * 8;
#pragma unroll
    for (int e2 = 0; e2 < 8; e2++) {
        int k = kk * 32 + hi * 8 + e2, d = jt * 16 + lo;
        float w = W[k * 64 + d];
        u16 h = f2bf(w);
        float r = w - bf2f(h);
        dh[base + e2] = h;
        dl[base + e2] = f2bf(r);
    }
}

// ---- node precompute v3: MFMA. 64 nodes/block (16/wave), hi/lo split A, 3-product fp32 accuracy.
// ns = s@Wsc (bf16 out), sv[n][c] = {s@Wup0, v0@Wup1, v1@Wup1, v2@Wup1}
__global__ __launch_bounds__(256) void node_prep_kernel(
    const float* __restrict__ node_feats, const u16* __restrict__ WNF,
    u16* __restrict__ ns_bf, f32x4* __restrict__ sv) {
    const int tid = threadIdx.x;
    const int lane = tid & 63;
    const int w = tid >> 6;
    const int lo16 = lane & 15;
    const int hi = lane >> 4;
    const int nb = blockIdx.x * 64 + w * 16;

    int an = nb + lo16; if (an > N_NODES - 1) an = N_NODES - 1;
    const float* arow = node_feats + (size_t)an * 256;

    const short8* B = (const short8*)WNF;
    // mat m (0=Wsc,1=Wup0,2=Wup1): hi frag at m*1024 + g*64 + lane, lo at +512

    f32x4 acc_ns[4], acc_su[4], acc_v[3][4];
#pragma unroll
    for (int jt = 0; jt < 4; jt++) {
        acc_ns[jt] = (f32x4)(0.0f);
        acc_su[jt] = (f32x4)(0.0f);
#pragma unroll
        for (int i = 0; i < 3; i++) acc_v[i][jt] = (f32x4)(0.0f);
    }

#pragma unroll
    for (int kk = 0; kk < 2; kk++) {
        short8 sh, sl;
        {
            const float* sp = arow + kk * 32 + hi * 8;
            f32x4 x0 = *(const f32x4*)sp;
            f32x4 x1 = *(const f32x4*)(sp + 4);
#pragma unroll
            for (int j = 0; j < 4; j++) {
                u16 h0 = f2bf(x0[j]);
                sh[j] = (short)h0;
                sl[j] = (short)f2bf(x0[j] - bf2f(h0));
                u16 h1 = f2bf(x1[j]);
                sh[4 + j] = (short)h1;
                sl[4 + j] = (short)f2bf(x1[j] - bf2f(h1));
            }
        }
        short8 vh[3], vl[3];
#pragma unroll
        for (int i = 0; i < 3; i++) {
            const float* vp = arow + 64 + i + 3 * (kk * 32 + hi * 8);
#pragma unroll
            for (int e = 0; e < 8; e++) {
                float x = vp[e * 3];
                u16 hb = f2bf(x);
                vh[i][e] = (short)hb;
                vl[i][e] = (short)f2bf(x - bf2f(hb));
            }
        }
#pragma unroll
        for (int jt = 0; jt < 4; jt++) {
            int fi = (kk * 4 + jt) * 64 + lane;
            short8 bh = B[fi], bl = B[512 + fi];
            acc_ns[jt] = mfma16(sh, bh, acc_ns[jt]);
            acc_ns[jt] = mfma16(sl, bh, acc_ns[jt]);
            acc_ns[jt] = mfma16(sh, bl, acc_ns[jt]);
            bh = B[1024 + fi]; bl = B[1536 + fi];
            acc_su[jt] = mfma16(sh, bh, acc_su[jt]);
            acc_su[jt] = mfma16(sl, bh, acc_su[jt]);
            acc_su[jt] = mfma16(sh, bl, acc_su[jt]);
            bh = B[2048 + fi]; bl = B[2560 + fi];
#pragma unroll
            for (int i = 0; i < 3; i++) {
                acc_v[i][jt] = mfma16(vh[i], bh, acc_v[i][jt]);
                acc_v[i][jt] = mfma16(vl[i], bh, acc_v[i][jt]);
                acc_v[i][jt] = mfma16(vh[i], bl, acc_v[i][jt]);
            }
        }
    }

#pragma unroll
    for (int r = 0; r < 4; r++) {
        int n = nb + hi * 4 + r;
        if (n < N_NODES) {
#pragma unroll
            for (int jt = 0; jt < 4; jt++) {
                int d = jt * 16 + lo16;
                ns_bf[(size_t)n * 64 + d] = f2bf(acc_ns[jt][r]);
                f32x4 o;
                o.x = acc_su[jt][r];
                o.y = acc_v[0][jt][r];
                o.z = acc_v[1][jt][r];
                o.w = acc_v[2][jt][r];
                sv[(size_t)n * 64 + d] = o;
            }
        }
    }
}

// ---- counting sort by rcv ----
__global__ void hist_kernel(const int* __restrict__ ei, int* __restrict__ cnt) {
    int e = blockIdx.x * 256 + threadIdx.x;
    if (e < N_EDGES) atomicAdd(&cnt[ei[N_EDGES + e]], 1);
}

__global__ void scan_kernel(const int* __restrict__ cnt, int* __restrict__ offs,
                            int* __restrict__ cursor) {
    __shared__ int buf[1024];
    int t = threadIdx.x;
    int base = t * 20;
    int loc[20];
    int tot = 0;
#pragma unroll
    for (int i = 0; i < 20; i++) {
        int idx = base + i;
        int v = (idx < N_NODES) ? cnt[idx] : 0;
        loc[i] = tot;
        tot += v;
    }
    buf[t] = tot;
    __syncthreads();
    for (int d = 1; d < 1024; d <<= 1) {
        int add = (t >= d) ? buf[t - d] : 0;
        __syncthreads();
        buf[t] += add;
        __syncthreads();
    }
    int ebase = buf[t] - tot;
#pragma unroll
    for (int i = 0; i < 20; i++) {
        int idx = base + i;
        if (idx < N_NODES) { int o = ebase + loc[i]; offs[idx] = o; cursor[idx] = o; }
    }
    if (t == 1023) offs[N_NODES] = buf[1023];
}

__global__ void scatter_kernel(const int* __restrict__ ei, int* __restrict__ cursor,
                               int* __restrict__ esort, int* __restrict__ ssort,
                               int* __restrict__ rsort) {
    int e = blockIdx.x * 256 + threadIdx.x;
    if (e < N_EDGES) {
        int sn = ei[e];
        int rc = ei[N_EDGES + e];
        int pos = atomicAdd(&cursor[rc], 1);
        esort[pos] = e;
        ssort[pos] = sn;
        rsort[pos] = rc;
    }
}

// ---- K3: edge MLP over all sorted edges (5000 blocks x 64 edges), bf16 MFMA ----
__global__ __launch_bounds__(256, 4) void mlp_kernel(
    const u16* __restrict__ ns_bf,
    const u16* __restrict__ W1f, const u16* __restrict__ W2f, const u16* __restrict__ W3f,
    const float* __restrict__ b1, const float* __restrict__ b2,
    const float* __restrict__ edge_feats, const float* __restrict__ lengths,
    const int* __restrict__ esort, const int* __restrict__ ssort, const int* __restrict__ rsort,
    u16* __restrict__ twg) {

    __shared__ u16 mlp[64][168];
    __shared__ u16 h1s[64][72];
    __shared__ u16 h2s[64][72];

    const int tid = threadIdx.x;
    const int l = tid & 63;
    const int lo16 = l & 15;
    const int hi = l >> 4;
    const int w = tid >> 6;
    const int erow = (w << 4) | lo16;
    const int koff = hi * 8;
    const int drow = (w << 4) + hi * 4;

    const int p0 = blockIdx.x * 64;    // E % 64 == 0: always a full tile

    const short8* w1frag = (const short8*)W1f;
    const short8* w2frag = (const short8*)W2f;
    const short8* w3frag = (const short8*)W3f;

    float bb1[4], bb2[4];
#pragma unroll
    for (int jt = 0; jt < 4; jt++) { bb1[jt] = b1[jt * 16 + lo16]; bb2[jt] = b2[jt * 16 + lo16]; }

    // zero pad region k=136..167
    {
        int rr = tid >> 2, pp = tid & 3;
        uint4 z = {0, 0, 0, 0};
        *(uint4*)&mlp[rr][136 + pp * 8] = z;
    }

    // stage gathered edge inputs
    {
        int es = tid >> 2, part = tid & 3;
        int e = esort[p0 + es];
        int sn = ssort[p0 + es];
        int rc = rsort[p0 + es];
        const uint4* ps = (const uint4*)(ns_bf + (size_t)sn * 64 + part * 16);
        uint4 s0 = ps[0], s1 = ps[1];
        *(uint4*)&mlp[es][part * 16] = s0;
        *(uint4*)&mlp[es][part * 16 + 8] = s1;
        const uint4* pr = (const uint4*)(ns_bf + (size_t)rc * 64 + part * 16);
        uint4 r0v = pr[0], r1v = pr[1];
        *(uint4*)&mlp[es][64 + part * 16] = r0v;
        *(uint4*)&mlp[es][64 + part * 16 + 8] = r1v;
        if (part == 0) {
            float4 f0 = *(const float4*)(edge_feats + (size_t)e * 8);
            float4 f1 = *(const float4*)(edge_feats + (size_t)e * 8 + 4);
            u32 pk0 = (u32)f2bf(f0.x) | ((u32)f2bf(f0.y) << 16);
            u32 pk1 = (u32)f2bf(f0.z) | ((u32)f2bf(f0.w) << 16);
            u32 pk2 = (u32)f2bf(f1.x) | ((u32)f2bf(f1.y) << 16);
            u32 pk3 = (u32)f2bf(f1.z) | ((u32)f2bf(f1.w) << 16);
            uint4 pk = {pk0, pk1, pk2, pk3};
            *(uint4*)&mlp[es][128] = pk;
            mlp[es][136] = f2bf(lengths[e]);
        }
    }
    __syncthreads();

    // layer 1: (64x160) @ (160x64)
    f32x4 a1c[4];
#pragma unroll
    for (int jt = 0; jt < 4; jt++) a1c[jt] = (f32x4)(0.0f);
#pragma unroll
    for (int kk = 0; kk < 5; kk++) {
        short8 af = *(const short8*)&mlp[erow][kk * 32 + koff];
        const short8* wb = w1frag + kk * 256 + l;
        a1c[0] = mfma16(af, wb[0],   a1c[0]);
        a1c[1] = mfma16(af, wb[64],  a1c[1]);
        a1c[2] = mfma16(af, wb[128], a1c[2]);
        a1c[3] = mfma16(af, wb[192], a1c[3]);
    }
#pragma unroll
    for (int jt = 0; jt < 4; jt++) {
#pragma unroll
        for (int r = 0; r < 4; r++) {
            float x = a1c[jt][r] + bb1[jt];
            h1s[drow + r][jt * 16 + lo16] = f2bf(silu(x));
        }
    }
    __syncthreads();

    // layer 2: (64x64) @ (64x64)
    f32x4 a2c[4];
#pragma unroll
    for (int jt = 0; jt < 4; jt++) a2c[jt] = (f32x4)(0.0f);
#pragma unroll
    for (int kk = 0; kk < 2; kk++) {
        short8 af = *(const short8*)&h1s[erow][kk * 32 + koff];
        const short8* wb = w2frag + kk * 256 + l;
        a2c[0] = mfma16(af, wb[0],   a2c[0]);
        a2c[1] = mfma16(af, wb[64],  a2c[1]);
        a2c[2] = mfma16(af, wb[128], a2c[2]);
        a2c[3] = mfma16(af, wb[192], a2c[3]);
    }
#pragma unroll
    for (int jt = 0; jt < 4; jt++) {
#pragma unroll
        for (int r = 0; r < 4; r++) {
            float x = a2c[jt][r] + bb2[jt];
            h2s[drow + r][jt * 16 + lo16] = f2bf(silu(x));
        }
    }
    __syncthreads();

    // layer 3: (64x64) @ (64x256)
    f32x4 tw[16];
#pragma unroll
    for (int jt = 0; jt < 16; jt++) tw[jt] = (f32x4)(0.0f);
#pragma unroll
    for (int kk = 0; kk < 2; kk++) {
        short8 af = *(const short8*)&h2s[erow][kk * 32 + koff];
        const short8* wb = w3frag + kk * 1024 + l;
#pragma unroll
        for (int jt = 0; jt < 16; jt++) tw[jt] = mfma16(af, wb[jt * 64], tw[jt]);
    }

    // store tw as fp16 (L2/L3-resident for seg)
    int relrow = p0 + drow;
#pragma unroll
    for (int r = 0; r < 4; r++) {
        u32 q0a = (u32)f2h(tw[0][r])  | ((u32)f2h(tw[1][r])  << 16);
        u32 q0b = (u32)f2h(tw[2][r])  | ((u32)f2h(tw[3][r])  << 16);
        u32 q1a = (u32)f2h(tw[4][r])  | ((u32)f2h(tw[5][r])  << 16);
        u32 q1b = (u32)f2h(tw[6][r])  | ((u32)f2h(tw[7][r])  << 16);
        u32 q2a = (u32)f2h(tw[8][r])  | ((u32)f2h(tw[9][r])  << 16);
        u32 q2b = (u32)f2h(tw[10][r]) | ((u32)f2h(tw[11][r]) << 16);
        u32 q3a = (u32)f2h(tw[12][r]) | ((u32)f2h(tw[13][r]) << 16);
        u32 q3b = (u32)f2h(tw[14][r]) | ((u32)f2h(tw[15][r]) << 16);
        u16* dst = twg + (size_t)(relrow + r) * 256 + lo16 * 16;
        u32x4v A = {q0a, q0b, q1a, q1b};
        u32x4v B = {q2a, q2b, q3a, q3b};
        *(u32x4v*)dst = A;
        *(((u32x4v*)dst) + 1) = B;
    }
}

// ---- K4: one wave per node; tensor products + register segment-sum ----
__global__ __launch_bounds__(256, 4) void seg_kernel(
    const f32x4* __restrict__ sv, const float* __restrict__ edge_attrs,
    const int* __restrict__ esort, const int* __restrict__ ssort,
    const int* __restrict__ offs, const u16* __restrict__ twg,
    float* __restrict__ m_g) {
    const int lane = threadIdx.x & 63;
    const int wv = threadIdx.x >> 6;
    const int n = blockIdx.x * 4 + wv;
    const int c = lane;
    const int jt = c >> 4, lo16 = c & 15;
    const int e0 = offs[n], e1 = offs[n + 1];
    float a_m0 = 0.f, a_m0b = 0.f;
    float a20 = 0.f, a21 = 0.f, a22 = 0.f, a30 = 0.f, a31 = 0.f, a32 = 0.f;
#pragma unroll 2
    for (int pos = e0; pos < e1; ++pos) {
        int e = esort[pos];
        int sn = ssort[pos];
        const u16* twp = twg + (size_t)pos * 256 + lo16 * 16;
        u32x4v ta = *((const u32x4v*)twp);
        u32x4v tb = *(((const u32x4v*)twp) + 1);
        f32x4 y4 = *(const f32x4*)(edge_attrs + (size_t)e * 4);
        f32x4 s4 = sv[(size_t)sn * 64 + c];
        u32 wwa = (jt & 2) ? ta.y : ta.x;
        u32 wwb = (jt & 2) ? ta.w : ta.z;
        u32 wwc = (jt & 2) ? tb.y : tb.x;
        u32 wwd = (jt & 2) ? tb.w : tb.z;
        int sh = (jt & 1) << 4;
        float w0 = h2f((wwa >> sh) & 0xffffu);
        float w1 = h2f((wwb >> sh) & 0xffffu);
        float w2 = h2f((wwc >> sh) & 0xffffu);
        float w3 = h2f((wwd >> sh) & 0xffffu);
        float xs = s4.x, xv0 = s4.y, xv1 = s4.z, xv2 = s4.w;
        float y0 = y4.x, ya = y4.y, yb = y4.z, yc = y4.w;
        a_m0 = fmaf(xs * y0, w0, a_m0);
        float dv = xv0 * ya + xv1 * yb + xv2 * yc;
        a_m0b = fmaf(dv, w1, a_m0b);
        float sw2 = xs * w2;
        a20 = fmaf(sw2, ya, a20); a21 = fmaf(sw2, yb, a21); a22 = fmaf(sw2, yc, a22);
        float yw3 = y0 * w3;
        a30 = fmaf(xv0, yw3, a30); a31 = fmaf(xv1, yw3, a31); a32 = fmaf(xv2, yw3, a32);
    }
    float* mr = m_g + (size_t)n * 512;
    ntstore(mr + c,        a_m0);
    ntstore(mr + 64 + c,   a_m0b * INV_SQRT3);
    ntstore(mr + 128 + c,  a20);
    ntstore(mr + 192 + c,  a30);
    ntstore(mr + 256 + c,  a21);
    ntstore(mr + 320 + c,  a31);
    ntstore(mr + 384 + c,  a22);
    ntstore(mr + 448 + c,  a32);
}

// ---- K5: MFMA epilogue. 64 nodes/block, 4 waves, no LDS, no barriers. ----
__global__ __launch_bounds__(256, 2) void out_kernel(
    const float* __restrict__ m_g, const u16* __restrict__ WSF,
    float* __restrict__ out) {
    const int tid = threadIdx.x;
    const int lane = tid & 63;
    const int w = tid >> 6;
    const int lo16 = lane & 15;
    const int hi = lane >> 4;
    const int nb = blockIdx.x * 64 + w * 16;

    int arow_n = nb + lo16;
    if (arow_n > N_NODES - 1) arow_n = N_NODES - 1;
    const float* arow = m_g + (size_t)arow_n * 512 + hi * 8;

    const short8* bsh = (const short8*)WSF;              // Ws hi
    const short8* bsl = (const short8*)(WSF + 8192);     // Ws lo
    const short8* bvh = (const short8*)(WSF + 16384);    // Wv hi
    const short8* bvl = (const short8*)(WSF + 24576);    // Wv lo

    f32x4 acc[4][4];
#pragma unroll
    for (int q = 0; q < 4; q++)
#pragma unroll
        for (int jt = 0; jt < 4; jt++) acc[q][jt] = (f32x4)(0.0f);

#pragma unroll
    for (int kk = 0; kk < 4; kk++) {
        short8 ahi[4], alo[4];
#pragma unroll
        for (int q = 0; q < 4; q++) {
            const float* p = arow + q * 128 + kk * 32;
            f32x4 x0 = ntload((const f32x4*)p);
            f32x4 x1 = ntload((const f32x4*)(p + 4));
#pragma unroll
            for (int j = 0; j < 4; j++) {
                u16 h0 = f2bf(x0[j]);
                ahi[q][j] = (short)h0;
                alo[q][j] = (short)f2bf(x0[j] - bf2f(h0));
                u16 h1 = f2bf(x1[j]);
                ahi[q][4 + j] = (short)h1;
                alo[q][4 + j] = (short)f2bf(x1[j] - bf2f(h1));
            }
        }
#pragma unroll
        for (int jt = 0; jt < 4; jt++) {
            int bidx = (kk * 4 + jt) * 64 + lane;
            short8 wh_s = bsh[bidx];
            short8 wl_s = bsl[bidx];
            short8 wh_v = bvh[bidx];
            short8 wl_v = bvl[bidx];
            acc[0][jt] = mfma16(ahi[0], wh_s, acc[0][jt]);
            acc[0][jt] = mfma16(alo[0], wh_s, acc[0][jt]);
            acc[0][jt] = mfma16(ahi[0], wl_s, acc[0][jt]);
#pragma unroll
            for (int q = 1; q < 4; q++) {
                acc[q][jt] = mfma16(ahi[q], wh_v, acc[q][jt]);
                acc[q][jt] = mfma16(alo[q], wh_v, acc[q][jt]);
                acc[q][jt] = mfma16(ahi[q], wl_v, acc[q][jt]);
            }
        }
    }

#pragma unroll
    for (int r = 0; r < 4; r++) {
        int n = nb + hi * 4 + r;
        if (n < N_NODES) {
#pragma unroll
            for (int jt = 0; jt < 4; jt++) {
                int d = jt * 16 + lo16;
                f32x4 o;
                o.x = acc[0][jt][r] * 0.0625f;
                o.y = acc[1][jt][r] * 0.0625f;
                o.z = acc[2][jt][r] * 0.0625f;
                o.w = acc[3][jt][r] * 0.0625f;
                ntstore((f32x4*)(out + (size_t)n * 256 + d * 4), o);
            }
        }
    }
}

extern "C" void kernel_launch(void* const* d_in, const int* in_sizes, int n_in,
                              void* d_out, int out_size, void* d_ws, size_t ws_size,
                              hipStream_t stream) {
    (void)in_sizes; (void)n_in; (void)out_size; (void)ws_size;
    const float* node_feats = (const float*)d_in[0];
    const float* edge_attrs = (const float*)d_in[1];
    const float* edge_feats = (const float*)d_in[2];
    const float* lengths    = (const float*)d_in[3];
    const int*   edge_index = (const int*)d_in[4];
    const float* Wsc  = (const float*)d_in[5];
    const float* Wup0 = (const float*)d_in[6];
    const float* Wup1 = (const float*)d_in[7];
    const float* W1   = (const float*)d_in[8];
    const float* b1   = (const float*)d_in[9];
    const float* W2   = (const float*)d_in[10];
    const float* b2   = (const float*)d_in[11];
    const float* W3   = (const float*)d_in[12];
    const float* Ws   = (const float*)d_in[13];
    const float* Wv   = (const float*)d_in[14];

    char* ws = (char*)d_ws;
    u16*   ns_bf  = (u16*)(ws + OFF_NSBF);
    f32x4* sv     = (f32x4*)(ws + OFF_SV);
    float* m_g    = (float*)(ws + OFF_MG);
    u16*   twg    = (u16*)(ws + OFF_TW);
    u16*   W1f    = (u16*)(ws + OFF_W1F);
    u16*   W2f    = (u16*)(ws + OFF_W2F);
    u16*   W3f    = (u16*)(ws + OFF_W3F);
    u16*   WNF    = (u16*)(ws + OFF_WNF);
    int*   cnt    = (int*)(ws + OFF_CNT);
    int*   offs   = (int*)(ws + OFF_OFFS);
    int*   cursor = (int*)(ws + OFF_CUR);
    u16*   WSF    = (u16*)(ws + OFF_CUR);   // reuses cursor region after scatter
    int*   esort  = (int*)(ws + OFF_ES);
    int*   ssort  = (int*)(ws + OFF_SS);
    int*   rsort  = (int*)(ws + OFF_RS);
    float* out    = (float*)d_out;

    (void)hipMemsetAsync(cnt, 0, N_NODES * sizeof(int), stream);
    prep_w_kernel<<<15, 256, 0, stream>>>(W1, W2, W3, W1f, W2f, W3f);
    prep_wn_kernel<<<6, 256, 0, stream>>>(Wsc, Wup0, Wup1, WNF);
    node_prep_kernel<<<(N_NODES + 63) / 64, 256, 0, stream>>>(node_feats, WNF, ns_bf, sv);
    hist_kernel<<<N_EDGES / 256, 256, 0, stream>>>(edge_index, cnt);
    scan_kernel<<<1, 1024, 0, stream>>>(cnt, offs, cursor);
    scatter_kernel<<<N_EDGES / 256, 256, 0, stream>>>(edge_index, cursor, esort, ssort, rsort);
    prep_w2_kernel<<<8, 256, 0, stream>>>(Ws, Wv, WSF);   // after scatter: cursor region is free

    mlp_kernel<<<N_EDGES / 64, 256, 0, stream>>>(ns_bf, W1f, W2f, W3f, b1, b2,
                                                 edge_feats, lengths,
                                                 esort, ssort, rsort, twg);
    seg_kernel<<<N_NODES / 4, 256, 0, stream>>>(sv, edge_attrs, esort, ssort,
                                                offs, twg, m_g);
    out_kernel<<<(N_NODES + 63) / 64, 256, 0, stream>>>(m_g, WSF, out);
}